// Round 12
// baseline (290.480 us; speedup 1.0000x reference)
//
#include <hip/hip_runtime.h>
#include <math.h>

#define N_NODES 20000
#define N_EDGES 400000
#define BATCH   4096
#define MTILES  (N_NODES / 16)   // 1250

typedef __attribute__((ext_vector_type(8))) short short8v;
typedef __attribute__((ext_vector_type(4))) float f32x4;

// ---- split fp32 into bf16 hi + bf16 lo (truncation; hi+lo ~ 16 mantissa bits)
__device__ __forceinline__ void bf16split(float v, short& h, short& l)
{
    unsigned u  = __float_as_uint(v);
    unsigned hu = u & 0xFFFF0000u;
    h = (short)(hu >> 16);
    const float lo = v - __uint_as_float(hu);
    l = (short)(__float_as_uint(lo) >> 16);
}

// ---- pack W[K][128] x2 (Wl,Wr) into B-fragments, bf16 hi/lo (once per layer).
// B-frag: lane&15 = N-col, k = (lane>>4)*8 + e. nt 0..7 = Wl, 8..15 = Wr.
template<int K>
__global__ __launch_bounds__(256)
void pack_w_kernel(const float* __restrict__ Wl, const float* __restrict__ Wr,
                   short* __restrict__ wpk)
{
    constexpr int KB = K / 32;
    const int t = blockIdx.x * 256 + threadIdx.x;
    if (t >= 16 * KB * 64) return;
    const int lane = t & 63;
    const int kb   = (t >> 6) % KB;
    const int nt   = t / (64 * KB);
    const float* W = (nt < 8) ? Wl : Wr;
    const int col  = (nt & 7) * 16 + (lane & 15);
    const int k0   = kb * 32 + (lane >> 4) * 8;
    short8v h, l;
#pragma unroll
    for (int e = 0; e < 8; ++e) {
        short hh, ll; bf16split(W[(size_t)(k0 + e) * 128 + col], hh, ll);
        h[e] = hh; l[e] = ll;
    }
    short* ob = wpk + ((size_t)(nt * KB + kb) * 2) * 512 + lane * 8;
    *(short8v*)ob         = h;
    *(short8v*)(ob + 512) = l;
}

// ---- MFMA transform with fused x packing: stage 16-node fp32 x-tile in LDS
// (row pad +4 -> 2-way ds_read conflicts only), split to bf16 hi/lo in-reg,
// bf16x3 compensation: acc = AhBh + AhBl + AlBh.
// D layout (m89-verified): col = lane&15, row = (lane>>4)*4 + reg.
template<int KB, int NWAVES>
__global__ __launch_bounds__(NWAVES * 64)
void mfma_transform_kernel(const float* __restrict__ x,
                           const short* __restrict__ wpk,
                           float* __restrict__ xl, float* __restrict__ xr)
{
    constexpr int K  = KB * 32;
    constexpr int KP = K + 4;
    __shared__ float xs[16 * KP];
    const int mtile = blockIdx.x;
    const int wid   = threadIdx.x >> 6;
    const int lane  = threadIdx.x & 63;

    // cooperative coalesced stage of x[mtile*16 .. +16][K]
    {
        const float4* __restrict__ src = (const float4*)(x + (size_t)mtile * 16 * K);
        for (int idx = threadIdx.x; idx < 16 * K / 4; idx += NWAVES * 64) {
            const int row = idx / (K / 4), c4 = idx % (K / 4);
            *(float4*)(xs + row * KP + c4 * 4) = src[idx];
        }
    }
    __syncthreads();

    // A-fragments from LDS: node = lane&15, k = kb*32 + (lane>>4)*8 + e
    short8v ah[KB], al[KB];
    {
        const float* ab = xs + (lane & 15) * KP + (lane >> 4) * 8;
#pragma unroll
        for (int kb = 0; kb < KB; ++kb) {
            const float4 f0 = *(const float4*)(ab + kb * 32);
            const float4 f1 = *(const float4*)(ab + kb * 32 + 4);
            float tmp[8] = {f0.x, f0.y, f0.z, f0.w, f1.x, f1.y, f1.z, f1.w};
#pragma unroll
            for (int e = 0; e < 8; ++e) {
                short hh, ll; bf16split(tmp[e], hh, ll);
                ah[kb][e] = hh; al[kb][e] = ll;
            }
        }
    }

#pragma unroll
    for (int i = 0; i < 4; ++i) {
        const int nt = wid * 4 + i;
        const short* bb = wpk + ((size_t)nt * KB * 2) * 512 + lane * 8;
        f32x4 acc = {0.f, 0.f, 0.f, 0.f};
#pragma unroll
        for (int kb = 0; kb < KB; ++kb) {
            const short8v bh = *(const short8v*)(bb + (size_t)(kb * 2 + 0) * 512);
            const short8v bl = *(const short8v*)(bb + (size_t)(kb * 2 + 1) * 512);
            acc = __builtin_amdgcn_mfma_f32_16x16x32_bf16(ah[kb], bh, acc, 0, 0, 0);
            acc = __builtin_amdgcn_mfma_f32_16x16x32_bf16(ah[kb], bl, acc, 0, 0, 0);
            acc = __builtin_amdgcn_mfma_f32_16x16x32_bf16(al[kb], bh, acc, 0, 0, 0);
        }
        float* out = (nt < 8) ? xl : xr;
        const int colb = (nt & 7) * 16 + (lane & 15);
        const int row0 = mtile * 16 + (lane >> 4) * 4;
#pragma unroll
        for (int r = 0; r < 4; ++r)
            out[(size_t)(row0 + r) * 128 + colb] = acc[r];
    }
}

// ---- layer-3 xr only for the 4096 pert rows (scalar, register-pipelined)
template<int K, int G>
__global__ __launch_bounds__(128)
void transform_r_pert_kernel(const float* __restrict__ x,
                             const int* __restrict__ pert,
                             const float* __restrict__ W,
                             float* __restrict__ out)
{
    const int t  = threadIdx.x;
    const int i0 = blockIdx.x * G;

    const float* __restrict__ xrow[G];
#pragma unroll
    for (int g = 0; g < G; ++g)
        xrow[g] = x + (size_t)pert[i0 + g] * K;

    float acc[G];
#pragma unroll
    for (int g = 0; g < G; ++g) acc[g] = 0.f;

    float4 xA[G], xB[G];
    float wA[4], wB[4];

    auto loadc = [&](float4* xs, float* w, int k) {
#pragma unroll
        for (int g = 0; g < G; ++g)
            xs[g] = *(const float4*)(xrow[g] + k);
#pragma unroll
        for (int u = 0; u < 4; ++u) w[u] = W[(k + u) * 128 + t];
    };
    auto fmac = [&](const float4* xs, const float* w) {
#pragma unroll
        for (int g = 0; g < G; ++g) {
            acc[g] = fmaf(xs[g].x, w[0], acc[g]);
            acc[g] = fmaf(xs[g].y, w[1], acc[g]);
            acc[g] = fmaf(xs[g].z, w[2], acc[g]);
            acc[g] = fmaf(xs[g].w, w[3], acc[g]);
        }
    };

    loadc(xA, wA, 0);
    for (int k0 = 0; k0 < K; k0 += 8) {
        if (k0 + 4 < K) loadc(xB, wB, k0 + 4);
        fmac(xA, wA);
        if (k0 + 8 < K) loadc(xA, wA, k0 + 8);
        fmac(xB, wB);
    }

#pragma unroll
    for (int g = 0; g < G; ++g)
        out[(size_t)(i0 + g) * 128 + t] = acc[g];
}

// ---- zero an int buffer
__global__ __launch_bounds__(256)
void zero_kernel(int* __restrict__ p, int n)
{
    const int i = blockIdx.x * blockDim.x + threadIdx.x;
    if (i < n) p[i] = 0;
}

// ---- CSR build: count degrees
__global__ __launch_bounds__(256)
void count_deg_kernel(const int* __restrict__ dst, int* __restrict__ deg, int E)
{
    const int e = blockIdx.x * blockDim.x + threadIdx.x;
    if (e < E) atomicAdd(&deg[dst[e]], 1);
}

// ---- exclusive scan over 20000 degrees; one block, LDS-staged coalesced I/O.
#define CHUNK 20
#define SCAN_PAD (1024 * CHUNK)
__global__ __launch_bounds__(1024)
void scan_kernel(const int* __restrict__ deg, int* __restrict__ off,
                 int* __restrict__ cursor)
{
    __shared__ int xs[SCAN_PAD];
    __shared__ int sums[1024];
    const int t = threadIdx.x;
    for (int i = t; i < SCAN_PAD; i += 1024)
        xs[i] = (i < N_NODES) ? deg[i] : 0;
    __syncthreads();

    const int base = t * CHUNK;
    int local[CHUNK];
    int s = 0;
#pragma unroll
    for (int i = 0; i < CHUNK; ++i) {
        local[i] = s;
        s += xs[base + i];
    }
    sums[t] = s;
    __syncthreads();
    for (int d = 1; d < 1024; d <<= 1) {
        int v = (t >= d) ? sums[t - d] : 0;
        __syncthreads();
        sums[t] += v;
        __syncthreads();
    }
    const int prev = (t == 0) ? 0 : sums[t - 1];
#pragma unroll
    for (int i = 0; i < CHUNK; ++i)
        xs[base + i] = prev + local[i];
    __syncthreads();
    for (int i = t; i < N_NODES; i += 1024) {
        const int o = xs[i];
        off[i] = o;
        cursor[i] = o;
    }
    if (t == 1023) off[N_NODES] = sums[1023];
}

// ---- scatter edges into dst-sorted order
__global__ __launch_bounds__(256)
void scatter_kernel(const int* __restrict__ src, const int* __restrict__ dst,
                    const float* __restrict__ ew, int* __restrict__ cursor,
                    int* __restrict__ ssrc, float* __restrict__ sew, int E)
{
    const int e = blockIdx.x * blockDim.x + threadIdx.x;
    if (e >= E) return;
    const int p = atomicAdd(&cursor[dst[e]], 1);
    ssrc[p] = src[e];
    sew[p]  = ew[e];
}

// ---- fused GATv2 layer: one wave per dst node, 8 edge slots in parallel.
// lane = q*8 + j : q = edge slot (8), j = dim chunk (8 dims, BOTH heads).
// Per edge: 8-lane group computes both head scores (3-shuffle reduce each),
// keeps two online-softmax states per lane. Rounds = ceil(deg/8).
template<int LAST>
__global__ __launch_bounds__(256)
void gat_node_kernel(const float* __restrict__ xl, const float* __restrict__ xr,
                     const int* __restrict__ off, const int* __restrict__ ssrc,
                     const float* __restrict__ sew, const float* __restrict__ a,
                     const float* __restrict__ b, float* __restrict__ xout,
                     const int* __restrict__ nodemap, int nnodes)
{
    const int widx = (int)((blockIdx.x * blockDim.x + threadIdx.x) >> 6);
    if (widx >= nnodes) return;
    const int node = LAST ? nodemap[widx] : widx;
    const int xrrow = widx;          // == node for !LAST; batch row for LAST
    const int lane = threadIdx.x & 63;
    const int q  = lane >> 3;        // edge slot
    const int j  = lane & 7;
    const int c0 = j * 8;            // head0 cols c0..c0+7; head1 cols c0+64..

    const float* xrp = xr + (size_t)xrrow * 128;
    const float4 r0 = *(const float4*)(xrp + c0);
    const float4 r1 = *(const float4*)(xrp + c0 + 4);
    const float4 r2 = *(const float4*)(xrp + c0 + 64);
    const float4 r3 = *(const float4*)(xrp + c0 + 68);
    const float4 a0 = *(const float4*)(a + c0);
    const float4 a1 = *(const float4*)(a + c0 + 4);
    const float4 a2 = *(const float4*)(a + c0 + 64);
    const float4 a3 = *(const float4*)(a + c0 + 68);

    const int e0 = off[node], e1 = off[node + 1];

    float m0 = -1e30f, m1 = -1e30f, s0 = 0.f, s1 = 0.f;
    float4 acc0 = {0,0,0,0}, acc1 = {0,0,0,0}, acc2 = {0,0,0,0}, acc3 = {0,0,0,0};

    auto lrelu4 = [](float4 v) {
        v.x = fmaxf(v.x, 0.2f * v.x); v.y = fmaxf(v.y, 0.2f * v.y);
        v.z = fmaxf(v.z, 0.2f * v.z); v.w = fmaxf(v.w, 0.2f * v.w);
        return v;
    };
    auto dot4 = [](float4 u, float4 v) {
        return fmaf(u.x, v.x, fmaf(u.y, v.y, fmaf(u.z, v.z, u.w * v.w)));
    };
    auto upd4 = [](float4 acc, float r, float c, float4 xv) {
        acc.x = fmaf(c, xv.x, acc.x * r); acc.y = fmaf(c, xv.y, acc.y * r);
        acc.z = fmaf(c, xv.z, acc.z * r); acc.w = fmaf(c, xv.w, acc.w * r);
        return acc;
    };

    for (int ebase = e0; ebase < e1; ebase += 8) {
        const int  ei    = ebase + q;
        const bool valid = ei < e1;
        const int  eic   = valid ? ei : (e1 - 1);
        const int  sn    = ssrc[eic];
        const float w    = valid ? sew[eic] : 0.f;
        const float* xp  = xl + (size_t)sn * 128;
        const float4 x0 = *(const float4*)(xp + c0);
        const float4 x1 = *(const float4*)(xp + c0 + 4);
        const float4 x2 = *(const float4*)(xp + c0 + 64);
        const float4 x3 = *(const float4*)(xp + c0 + 68);

        const float4 v0 = lrelu4(make_float4(x0.x + r0.x, x0.y + r0.y, x0.z + r0.z, x0.w + r0.w));
        const float4 v1 = lrelu4(make_float4(x1.x + r1.x, x1.y + r1.y, x1.z + r1.z, x1.w + r1.w));
        const float4 v2 = lrelu4(make_float4(x2.x + r2.x, x2.y + r2.y, x2.z + r2.z, x2.w + r2.w));
        const float4 v3 = lrelu4(make_float4(x3.x + r3.x, x3.y + r3.y, x3.z + r3.z, x3.w + r3.w));

        float p0 = dot4(v0, a0) + dot4(v1, a1);
        float p1 = dot4(v2, a2) + dot4(v3, a3);
        p0 += __shfl_xor(p0, 1, 64); p1 += __shfl_xor(p1, 1, 64);
        p0 += __shfl_xor(p0, 2, 64); p1 += __shfl_xor(p1, 2, 64);
        p0 += __shfl_xor(p0, 4, 64); p1 += __shfl_xor(p1, 4, 64);
        p0 = valid ? p0 : -1e30f;
        p1 = valid ? p1 : -1e30f;

        // online softmax head 0
        {
            const float d   = p0 - m0;
            const float t   = __expf(-fabsf(d));
            const bool  pos = d > 0.f;
            const float r   = pos ? t : 1.f;
            const float ex  = pos ? 1.f : t;
            m0 = pos ? p0 : m0;
            const float c = ex * w;
            s0 = s0 * r + ex;
            acc0 = upd4(acc0, r, c, x0);
            acc1 = upd4(acc1, r, c, x1);
        }
        // head 1
        {
            const float d   = p1 - m1;
            const float t   = __expf(-fabsf(d));
            const bool  pos = d > 0.f;
            const float r   = pos ? t : 1.f;
            const float ex  = pos ? 1.f : t;
            m1 = pos ? p1 : m1;
            const float c = ex * w;
            s1 = s1 * r + ex;
            acc2 = upd4(acc2, r, c, x2);
            acc3 = upd4(acc3, r, c, x3);
        }
    }

    // ---- merge the 8 slot states (across q: lane strides 8, 16, 32)
    auto redmax = [](float v) {
        v = fmaxf(v, __shfl_xor(v, 8, 64));
        v = fmaxf(v, __shfl_xor(v, 16, 64));
        return fmaxf(v, __shfl_xor(v, 32, 64));
    };
    auto redsum = [](float v) {
        v += __shfl_xor(v, 8, 64);
        v += __shfl_xor(v, 16, 64);
        return v + __shfl_xor(v, 32, 64);
    };
    const float mg0 = redmax(m0), mg1 = redmax(m1);
    const float rq0 = __expf(m0 - mg0), rq1 = __expf(m1 - mg1);
    const float sq0 = redsum(s0 * rq0), sq1 = redsum(s1 * rq1);
    auto redacc = [&](float4 acc, float rq) {
        acc.x = redsum(acc.x * rq); acc.y = redsum(acc.y * rq);
        acc.z = redsum(acc.z * rq); acc.w = redsum(acc.w * rq);
        return acc;
    };
    acc0 = redacc(acc0, rq0); acc1 = redacc(acc1, rq0);
    acc2 = redacc(acc2, rq1); acc3 = redacc(acc3, rq1);
    const float inv0 = 1.f / (sq0 + 1e-16f);
    const float inv1 = 1.f / (sq1 + 1e-16f);

    if (q != 0) return;
    if (!LAST) {
        const float4 b0 = *(const float4*)(b + c0);
        const float4 b1 = *(const float4*)(b + c0 + 4);
        const float4 b2 = *(const float4*)(b + c0 + 64);
        const float4 b3 = *(const float4*)(b + c0 + 68);
        auto fin = [](float4 acc, float inv, float4 bb) {
            float4 o;
            o.x = acc.x * inv + bb.x; o.x = o.x > 0.f ? o.x : expm1f(o.x);
            o.y = acc.y * inv + bb.y; o.y = o.y > 0.f ? o.y : expm1f(o.y);
            o.z = acc.z * inv + bb.z; o.z = o.z > 0.f ? o.z : expm1f(o.z);
            o.w = acc.w * inv + bb.w; o.w = o.w > 0.f ? o.w : expm1f(o.w);
            return o;
        };
        float* op = xout + (size_t)node * 128;
        *(float4*)(op + c0)      = fin(acc0, inv0, b0);
        *(float4*)(op + c0 + 4)  = fin(acc1, inv0, b1);
        *(float4*)(op + c0 + 64) = fin(acc2, inv1, b2);
        *(float4*)(op + c0 + 68) = fin(acc3, inv1, b3);
    } else {
        const float4 b0 = *(const float4*)(b + c0);
        const float4 b1 = *(const float4*)(b + c0 + 4);
        float4 o0, o1;
        o0.x = 0.5f * (acc0.x * inv0 + acc2.x * inv1) + b0.x;
        o0.y = 0.5f * (acc0.y * inv0 + acc2.y * inv1) + b0.y;
        o0.z = 0.5f * (acc0.z * inv0 + acc2.z * inv1) + b0.z;
        o0.w = 0.5f * (acc0.w * inv0 + acc2.w * inv1) + b0.w;
        o1.x = 0.5f * (acc1.x * inv0 + acc3.x * inv1) + b1.x;
        o1.y = 0.5f * (acc1.y * inv0 + acc3.y * inv1) + b1.y;
        o1.z = 0.5f * (acc1.z * inv0 + acc3.z * inv1) + b1.z;
        o1.w = 0.5f * (acc1.w * inv0 + acc3.w * inv1) + b1.w;
        float* op = xout + (size_t)widx * 64;
        *(float4*)(op + c0)     = o0;
        *(float4*)(op + c0 + 4) = o1;
    }
}

extern "C" void kernel_launch(void* const* d_in, const int* in_sizes, int n_in,
                              void* d_out, int out_size, void* d_ws, size_t ws_size,
                              hipStream_t stream)
{
    const int*   pert = (const int*)d_in[0];
    const int*   eidx = (const int*)d_in[1];
    const float* ew   = (const float*)d_in[2];
    const float* emb  = (const float*)d_in[3];
    const float* Wl[4] = {(const float*)d_in[4],  (const float*)d_in[8],
                          (const float*)d_in[12], (const float*)d_in[16]};
    const float* Wr[4] = {(const float*)d_in[5],  (const float*)d_in[9],
                          (const float*)d_in[13], (const float*)d_in[17]};
    const float* av[4] = {(const float*)d_in[6],  (const float*)d_in[10],
                          (const float*)d_in[14], (const float*)d_in[18]};
    const float* bv[4] = {(const float*)d_in[7],  (const float*)d_in[11],
                          (const float*)d_in[15], (const float*)d_in[19]};

    const int N = N_NODES, E = N_EDGES;
    const int* srcp = eidx;
    const int* dstp = eidx + E;

    // workspace layout
    float* ws   = (float*)d_ws;
    float* xbuf = ws;                               // N*128 f
    float* xl   = xbuf + (size_t)N * 128;           // N*128 f
    float* xr   = xl   + (size_t)N * 128;           // N*128 f
    short* wpk  = (short*)(xr + (size_t)N * 128);   // 4 layers x 65536 shorts
    int*   deg  = (int*)(wpk + 4 * 65536);          // N
    int*   off  = deg + N;                          // N+1
    int*   cur  = off + N + 1;                      // N
    int*   ssrc = cur + N;                          // E
    float* sew  = (float*)(ssrc + E);               // E

    // ---- build dst-sorted CSR once
    zero_kernel<<<(N + 255) / 256, 256, 0, stream>>>(deg, N);
    count_deg_kernel<<<(E + 255) / 256, 256, 0, stream>>>(dstp, deg, E);
    scan_kernel<<<1, 1024, 0, stream>>>(deg, off, cur);
    scatter_kernel<<<(E + 255) / 256, 256, 0, stream>>>(srcp, dstp, ew, cur,
                                                        ssrc, sew, E);

    // ---- pack all W fragments (bf16 hi/lo) once
    pack_w_kernel<64><<<8,  256, 0, stream>>>(Wl[0], Wr[0], wpk);
    pack_w_kernel<128><<<16, 256, 0, stream>>>(Wl[1], Wr[1], wpk + 1 * 65536);
    pack_w_kernel<128><<<16, 256, 0, stream>>>(Wl[2], Wr[2], wpk + 2 * 65536);
    pack_w_kernel<128><<<16, 256, 0, stream>>>(Wl[3], Wr[3], wpk + 3 * 65536);

    // ---- layer 0 (K=64)
    mfma_transform_kernel<2, 4><<<MTILES, 256, 0, stream>>>(emb, wpk, xl, xr);
    gat_node_kernel<0><<<(N * 64 + 255) / 256, 256, 0, stream>>>(
        xl, xr, off, ssrc, sew, av[0], bv[0], xbuf, nullptr, N);

    // ---- layers 1,2 (K=128)
    for (int layer = 1; layer < 3; ++layer) {
        mfma_transform_kernel<4, 4><<<MTILES, 256, 0, stream>>>(
            xbuf, wpk + layer * 65536, xl, xr);
        gat_node_kernel<0><<<(N * 64 + 255) / 256, 256, 0, stream>>>(
            xl, xr, off, ssrc, sew, av[layer], bv[layer], xbuf, nullptr, N);
    }

    // ---- layer 3: xl for all nodes (MFMA, 8 l-tiles); xr only for pert rows
    mfma_transform_kernel<4, 2><<<MTILES, 128, 0, stream>>>(
        xbuf, wpk + 3 * 65536, xl, xr);
    transform_r_pert_kernel<128, 8><<<BATCH / 8, 128, 0, stream>>>(
        xbuf, pert, Wr[3], xr);
    gat_node_kernel<1><<<(BATCH * 64 + 255) / 256, 256, 0, stream>>>(
        xl, xr, off, ssrc, sew, av[3], bv[3], (float*)d_out, pert, BATCH);
}

// Round 13
// 280.298 us; speedup vs baseline: 1.0363x; 1.0363x over previous
//
#include <hip/hip_runtime.h>
#include <hip/hip_fp16.h>
#include <math.h>

#define N_NODES 20000
#define N_EDGES 400000
#define BATCH   4096
#define MTILES  (N_NODES / 16)   // 1250
#define XSCALE  1024.0f
#define XINV    (1.0f / 1024.0f)

typedef __attribute__((ext_vector_type(8))) short short8v;
typedef __attribute__((ext_vector_type(4))) float f32x4;

// ---- split fp32 into bf16 hi + bf16 lo (truncation; hi+lo ~ 16 mantissa bits)
__device__ __forceinline__ void bf16split(float v, short& h, short& l)
{
    unsigned u  = __float_as_uint(v);
    unsigned hu = u & 0xFFFF0000u;
    h = (short)(hu >> 16);
    const float lo = v - __uint_as_float(hu);
    l = (short)(__float_as_uint(lo) >> 16);
}

// ---- pack W[K][128] x2 (Wl,Wr) into B-fragments, bf16 hi/lo (once per layer).
// B-frag: lane&15 = N-col, k = (lane>>4)*8 + e. nt 0..7 = Wl, 8..15 = Wr.
template<int K>
__global__ __launch_bounds__(256)
void pack_w_kernel(const float* __restrict__ Wl, const float* __restrict__ Wr,
                   short* __restrict__ wpk)
{
    constexpr int KB = K / 32;
    const int t = blockIdx.x * 256 + threadIdx.x;
    if (t >= 16 * KB * 64) return;
    const int lane = t & 63;
    const int kb   = (t >> 6) % KB;
    const int nt   = t / (64 * KB);
    const float* W = (nt < 8) ? Wl : Wr;
    const int col  = (nt & 7) * 16 + (lane & 15);
    const int k0   = kb * 32 + (lane >> 4) * 8;
    short8v h, l;
#pragma unroll
    for (int e = 0; e < 8; ++e) {
        short hh, ll; bf16split(W[(size_t)(k0 + e) * 128 + col], hh, ll);
        h[e] = hh; l[e] = ll;
    }
    short* ob = wpk + ((size_t)(nt * KB + kb) * 2) * 512 + lane * 8;
    *(short8v*)ob         = h;
    *(short8v*)(ob + 512) = l;
}

// ---- MFMA transform with fused x packing (LDS stage, bf16 hi/lo in-reg,
// bf16x3 compensation). xl tiles written as fp16 * XSCALE (gat gathers them;
// fp16 halves the random-gather working set -> L2-resident). xr stays fp32.
// D layout (m89-verified): col = lane&15, row = (lane>>4)*4 + reg.
template<int KB, int NWAVES>
__global__ __launch_bounds__(NWAVES * 64)
void mfma_transform_kernel(const float* __restrict__ x,
                           const short* __restrict__ wpk,
                           __half* __restrict__ xlh, float* __restrict__ xr)
{
    constexpr int K  = KB * 32;
    constexpr int KP = K + 4;
    __shared__ float xs[16 * KP];
    const int mtile = blockIdx.x;
    const int wid   = threadIdx.x >> 6;
    const int lane  = threadIdx.x & 63;

    {
        const float4* __restrict__ src = (const float4*)(x + (size_t)mtile * 16 * K);
        for (int idx = threadIdx.x; idx < 16 * K / 4; idx += NWAVES * 64) {
            const int row = idx / (K / 4), c4 = idx % (K / 4);
            *(float4*)(xs + row * KP + c4 * 4) = src[idx];
        }
    }
    __syncthreads();

    short8v ah[KB], al[KB];
    {
        const float* ab = xs + (lane & 15) * KP + (lane >> 4) * 8;
#pragma unroll
        for (int kb = 0; kb < KB; ++kb) {
            const float4 f0 = *(const float4*)(ab + kb * 32);
            const float4 f1 = *(const float4*)(ab + kb * 32 + 4);
            float tmp[8] = {f0.x, f0.y, f0.z, f0.w, f1.x, f1.y, f1.z, f1.w};
#pragma unroll
            for (int e = 0; e < 8; ++e) {
                short hh, ll; bf16split(tmp[e], hh, ll);
                ah[kb][e] = hh; al[kb][e] = ll;
            }
        }
    }

#pragma unroll
    for (int i = 0; i < 4; ++i) {
        const int nt = wid * 4 + i;
        const short* bb = wpk + ((size_t)nt * KB * 2) * 512 + lane * 8;
        f32x4 acc = {0.f, 0.f, 0.f, 0.f};
#pragma unroll
        for (int kb = 0; kb < KB; ++kb) {
            const short8v bh = *(const short8v*)(bb + (size_t)(kb * 2 + 0) * 512);
            const short8v bl = *(const short8v*)(bb + (size_t)(kb * 2 + 1) * 512);
            acc = __builtin_amdgcn_mfma_f32_16x16x32_bf16(ah[kb], bh, acc, 0, 0, 0);
            acc = __builtin_amdgcn_mfma_f32_16x16x32_bf16(ah[kb], bl, acc, 0, 0, 0);
            acc = __builtin_amdgcn_mfma_f32_16x16x32_bf16(al[kb], bh, acc, 0, 0, 0);
        }
        const int colb = (nt & 7) * 16 + (lane & 15);
        const int row0 = mtile * 16 + (lane >> 4) * 4;
        if (nt < 8) {
#pragma unroll
            for (int r = 0; r < 4; ++r)
                xlh[(size_t)(row0 + r) * 128 + colb] = __float2half(acc[r] * XSCALE);
        } else {
#pragma unroll
            for (int r = 0; r < 4; ++r)
                xr[(size_t)(row0 + r) * 128 + colb] = acc[r];
        }
    }
}

// ---- layer-3 xr only for the 4096 pert rows (scalar, register-pipelined)
template<int K, int G>
__global__ __launch_bounds__(128)
void transform_r_pert_kernel(const float* __restrict__ x,
                             const int* __restrict__ pert,
                             const float* __restrict__ W,
                             float* __restrict__ out)
{
    const int t  = threadIdx.x;
    const int i0 = blockIdx.x * G;

    const float* __restrict__ xrow[G];
#pragma unroll
    for (int g = 0; g < G; ++g)
        xrow[g] = x + (size_t)pert[i0 + g] * K;

    float acc[G];
#pragma unroll
    for (int g = 0; g < G; ++g) acc[g] = 0.f;

    float4 xA[G], xB[G];
    float wA[4], wB[4];

    auto loadc = [&](float4* xs, float* w, int k) {
#pragma unroll
        for (int g = 0; g < G; ++g)
            xs[g] = *(const float4*)(xrow[g] + k);
#pragma unroll
        for (int u = 0; u < 4; ++u) w[u] = W[(k + u) * 128 + t];
    };
    auto fmac = [&](const float4* xs, const float* w) {
#pragma unroll
        for (int g = 0; g < G; ++g) {
            acc[g] = fmaf(xs[g].x, w[0], acc[g]);
            acc[g] = fmaf(xs[g].y, w[1], acc[g]);
            acc[g] = fmaf(xs[g].z, w[2], acc[g]);
            acc[g] = fmaf(xs[g].w, w[3], acc[g]);
        }
    };

    loadc(xA, wA, 0);
    for (int k0 = 0; k0 < K; k0 += 8) {
        if (k0 + 4 < K) loadc(xB, wB, k0 + 4);
        fmac(xA, wA);
        if (k0 + 8 < K) loadc(xA, wA, k0 + 8);
        fmac(xB, wB);
    }

#pragma unroll
    for (int g = 0; g < G; ++g)
        out[(size_t)(i0 + g) * 128 + t] = acc[g];
}

// ---- zero an int buffer
__global__ __launch_bounds__(256)
void zero_kernel(int* __restrict__ p, int n)
{
    const int i = blockIdx.x * blockDim.x + threadIdx.x;
    if (i < n) p[i] = 0;
}

// ---- CSR build: count degrees
__global__ __launch_bounds__(256)
void count_deg_kernel(const int* __restrict__ dst, int* __restrict__ deg, int E)
{
    const int e = blockIdx.x * blockDim.x + threadIdx.x;
    if (e < E) atomicAdd(&deg[dst[e]], 1);
}

// ---- exclusive scan over 20000 degrees; one block, LDS-staged coalesced I/O.
#define CHUNK 20
#define SCAN_PAD (1024 * CHUNK)
__global__ __launch_bounds__(1024)
void scan_kernel(const int* __restrict__ deg, int* __restrict__ off,
                 int* __restrict__ cursor)
{
    __shared__ int xs[SCAN_PAD];
    __shared__ int sums[1024];
    const int t = threadIdx.x;
    for (int i = t; i < SCAN_PAD; i += 1024)
        xs[i] = (i < N_NODES) ? deg[i] : 0;
    __syncthreads();

    const int base = t * CHUNK;
    int local[CHUNK];
    int s = 0;
#pragma unroll
    for (int i = 0; i < CHUNK; ++i) {
        local[i] = s;
        s += xs[base + i];
    }
    sums[t] = s;
    __syncthreads();
    for (int d = 1; d < 1024; d <<= 1) {
        int v = (t >= d) ? sums[t - d] : 0;
        __syncthreads();
        sums[t] += v;
        __syncthreads();
    }
    const int prev = (t == 0) ? 0 : sums[t - 1];
#pragma unroll
    for (int i = 0; i < CHUNK; ++i)
        xs[base + i] = prev + local[i];
    __syncthreads();
    for (int i = t; i < N_NODES; i += 1024) {
        const int o = xs[i];
        off[i] = o;
        cursor[i] = o;
    }
    if (t == 1023) off[N_NODES] = sums[1023];
}

// ---- scatter edges into dst-sorted order
__global__ __launch_bounds__(256)
void scatter_kernel(const int* __restrict__ src, const int* __restrict__ dst,
                    const float* __restrict__ ew, int* __restrict__ cursor,
                    int* __restrict__ ssrc, float* __restrict__ sew, int E)
{
    const int e = blockIdx.x * blockDim.x + threadIdx.x;
    if (e >= E) return;
    const int p = atomicAdd(&cursor[dst[e]], 1);
    ssrc[p] = src[e];
    sew[p]  = ew[e];
}

// ---- fused GATv2 layer: one wave per dst node, 8 edge slots in parallel.
// lane = q*8 + j. xl is fp16 * XSCALE: 16B gather/lane/edge, 5.1MB working set
// (~L2-resident). lrelu is positively homogeneous -> compute scores in scaled
// space, multiply reduced dot by XINV before softmax (exact); XINV folded into
// the 1/s normalizer for messages.
template<int LAST>
__global__ __launch_bounds__(256)
void gat_node_kernel(const __half* __restrict__ xl, const float* __restrict__ xr,
                     const int* __restrict__ off, const int* __restrict__ ssrc,
                     const float* __restrict__ sew, const float* __restrict__ a,
                     const float* __restrict__ b, float* __restrict__ xout,
                     const int* __restrict__ nodemap, int nnodes)
{
    const int widx = (int)((blockIdx.x * blockDim.x + threadIdx.x) >> 6);
    if (widx >= nnodes) return;
    const int node = LAST ? nodemap[widx] : widx;
    const int xrrow = widx;          // == node for !LAST; batch row for LAST
    const int lane = threadIdx.x & 63;
    const int q  = lane >> 3;        // edge slot
    const int j  = lane & 7;
    const int c0 = j * 8;            // head0 cols c0..c0+7; head1 cols c0+64..

    auto scale4 = [](float4 v) {
        return make_float4(v.x * XSCALE, v.y * XSCALE, v.z * XSCALE, v.w * XSCALE);
    };
    const float* xrp = xr + (size_t)xrrow * 128;
    const float4 r0 = scale4(*(const float4*)(xrp + c0));
    const float4 r1 = scale4(*(const float4*)(xrp + c0 + 4));
    const float4 r2 = scale4(*(const float4*)(xrp + c0 + 64));
    const float4 r3 = scale4(*(const float4*)(xrp + c0 + 68));
    const float4 a0 = *(const float4*)(a + c0);
    const float4 a1 = *(const float4*)(a + c0 + 4);
    const float4 a2 = *(const float4*)(a + c0 + 64);
    const float4 a3 = *(const float4*)(a + c0 + 68);

    const int e0 = off[node], e1 = off[node + 1];

    float m0 = -1e30f, m1 = -1e30f, s0 = 0.f, s1 = 0.f;
    float4 acc0 = {0,0,0,0}, acc1 = {0,0,0,0}, acc2 = {0,0,0,0}, acc3 = {0,0,0,0};

    auto ldh8 = [](const __half* p, float4& lo, float4& hi) {
        const uint4 raw = *(const uint4*)p;   // one dwordx4 = 8 fp16
        const float2 f0 = __half22float2(*(const __half2*)&raw.x);
        const float2 f1 = __half22float2(*(const __half2*)&raw.y);
        const float2 f2 = __half22float2(*(const __half2*)&raw.z);
        const float2 f3 = __half22float2(*(const __half2*)&raw.w);
        lo = make_float4(f0.x, f0.y, f1.x, f1.y);
        hi = make_float4(f2.x, f2.y, f3.x, f3.y);
    };
    auto lrelu4 = [](float4 v) {
        v.x = fmaxf(v.x, 0.2f * v.x); v.y = fmaxf(v.y, 0.2f * v.y);
        v.z = fmaxf(v.z, 0.2f * v.z); v.w = fmaxf(v.w, 0.2f * v.w);
        return v;
    };
    auto dot4 = [](float4 u, float4 v) {
        return fmaf(u.x, v.x, fmaf(u.y, v.y, fmaf(u.z, v.z, u.w * v.w)));
    };
    auto upd4 = [](float4 acc, float r, float c, float4 xv) {
        acc.x = fmaf(c, xv.x, acc.x * r); acc.y = fmaf(c, xv.y, acc.y * r);
        acc.z = fmaf(c, xv.z, acc.z * r); acc.w = fmaf(c, xv.w, acc.w * r);
        return acc;
    };

    for (int ebase = e0; ebase < e1; ebase += 8) {
        const int  ei    = ebase + q;
        const bool valid = ei < e1;
        const int  eic   = valid ? ei : (e1 - 1);
        const int  sn    = ssrc[eic];
        const float w    = valid ? sew[eic] : 0.f;
        const __half* xp = xl + (size_t)sn * 128;
        float4 x0, x1, x2, x3;
        ldh8(xp + c0,      x0, x1);   // head0: scaled fp32
        ldh8(xp + c0 + 64, x2, x3);   // head1

        const float4 v0 = lrelu4(make_float4(x0.x + r0.x, x0.y + r0.y, x0.z + r0.z, x0.w + r0.w));
        const float4 v1 = lrelu4(make_float4(x1.x + r1.x, x1.y + r1.y, x1.z + r1.z, x1.w + r1.w));
        const float4 v2 = lrelu4(make_float4(x2.x + r2.x, x2.y + r2.y, x2.z + r2.z, x2.w + r2.w));
        const float4 v3 = lrelu4(make_float4(x3.x + r3.x, x3.y + r3.y, x3.z + r3.z, x3.w + r3.w));

        float p0 = dot4(v0, a0) + dot4(v1, a1);
        float p1 = dot4(v2, a2) + dot4(v3, a3);
        p0 += __shfl_xor(p0, 1, 64); p1 += __shfl_xor(p1, 1, 64);
        p0 += __shfl_xor(p0, 2, 64); p1 += __shfl_xor(p1, 2, 64);
        p0 += __shfl_xor(p0, 4, 64); p1 += __shfl_xor(p1, 4, 64);
        p0 = valid ? p0 * XINV : -1e30f;   // back to true score space (exact op)
        p1 = valid ? p1 * XINV : -1e30f;

        // online softmax head 0 (acc stays in scaled message space)
        {
            const float d   = p0 - m0;
            const float t   = __expf(-fabsf(d));
            const bool  pos = d > 0.f;
            const float r   = pos ? t : 1.f;
            const float ex  = pos ? 1.f : t;
            m0 = pos ? p0 : m0;
            const float c = ex * w;
            s0 = s0 * r + ex;
            acc0 = upd4(acc0, r, c, x0);
            acc1 = upd4(acc1, r, c, x1);
        }
        // head 1
        {
            const float d   = p1 - m1;
            const float t   = __expf(-fabsf(d));
            const bool  pos = d > 0.f;
            const float r   = pos ? t : 1.f;
            const float ex  = pos ? 1.f : t;
            m1 = pos ? p1 : m1;
            const float c = ex * w;
            s1 = s1 * r + ex;
            acc2 = upd4(acc2, r, c, x2);
            acc3 = upd4(acc3, r, c, x3);
        }
    }

    // ---- merge the 8 slot states (across q: lane strides 8, 16, 32)
    auto redmax = [](float v) {
        v = fmaxf(v, __shfl_xor(v, 8, 64));
        v = fmaxf(v, __shfl_xor(v, 16, 64));
        return fmaxf(v, __shfl_xor(v, 32, 64));
    };
    auto redsum = [](float v) {
        v += __shfl_xor(v, 8, 64);
        v += __shfl_xor(v, 16, 64);
        return v + __shfl_xor(v, 32, 64);
    };
    const float mg0 = redmax(m0), mg1 = redmax(m1);
    const float rq0 = __expf(m0 - mg0), rq1 = __expf(m1 - mg1);
    const float sq0 = redsum(s0 * rq0), sq1 = redsum(s1 * rq1);
    auto redacc = [&](float4 acc, float rq) {
        acc.x = redsum(acc.x * rq); acc.y = redsum(acc.y * rq);
        acc.z = redsum(acc.z * rq); acc.w = redsum(acc.w * rq);
        return acc;
    };
    acc0 = redacc(acc0, rq0); acc1 = redacc(acc1, rq0);
    acc2 = redacc(acc2, rq1); acc3 = redacc(acc3, rq1);
    const float inv0 = XINV / (sq0 + 1e-16f);   // undo message scaling here
    const float inv1 = XINV / (sq1 + 1e-16f);

    if (q != 0) return;
    if (!LAST) {
        const float4 b0 = *(const float4*)(b + c0);
        const float4 b1 = *(const float4*)(b + c0 + 4);
        const float4 b2 = *(const float4*)(b + c0 + 64);
        const float4 b3 = *(const float4*)(b + c0 + 68);
        auto fin = [](float4 acc, float inv, float4 bb) {
            float4 o;
            o.x = acc.x * inv + bb.x; o.x = o.x > 0.f ? o.x : expm1f(o.x);
            o.y = acc.y * inv + bb.y; o.y = o.y > 0.f ? o.y : expm1f(o.y);
            o.z = acc.z * inv + bb.z; o.z = o.z > 0.f ? o.z : expm1f(o.z);
            o.w = acc.w * inv + bb.w; o.w = o.w > 0.f ? o.w : expm1f(o.w);
            return o;
        };
        float* op = xout + (size_t)node * 128;
        *(float4*)(op + c0)      = fin(acc0, inv0, b0);
        *(float4*)(op + c0 + 4)  = fin(acc1, inv0, b1);
        *(float4*)(op + c0 + 64) = fin(acc2, inv1, b2);
        *(float4*)(op + c0 + 68) = fin(acc3, inv1, b3);
    } else {
        const float4 b0 = *(const float4*)(b + c0);
        const float4 b1 = *(const float4*)(b + c0 + 4);
        float4 o0, o1;
        o0.x = 0.5f * (acc0.x * inv0 + acc2.x * inv1) + b0.x;
        o0.y = 0.5f * (acc0.y * inv0 + acc2.y * inv1) + b0.y;
        o0.z = 0.5f * (acc0.z * inv0 + acc2.z * inv1) + b0.z;
        o0.w = 0.5f * (acc0.w * inv0 + acc2.w * inv1) + b0.w;
        o1.x = 0.5f * (acc1.x * inv0 + acc3.x * inv1) + b1.x;
        o1.y = 0.5f * (acc1.y * inv0 + acc3.y * inv1) + b1.y;
        o1.z = 0.5f * (acc1.z * inv0 + acc3.z * inv1) + b1.z;
        o1.w = 0.5f * (acc1.w * inv0 + acc3.w * inv1) + b1.w;
        float* op = xout + (size_t)widx * 64;
        *(float4*)(op + c0)     = o0;
        *(float4*)(op + c0 + 4) = o1;
    }
}

extern "C" void kernel_launch(void* const* d_in, const int* in_sizes, int n_in,
                              void* d_out, int out_size, void* d_ws, size_t ws_size,
                              hipStream_t stream)
{
    const int*   pert = (const int*)d_in[0];
    const int*   eidx = (const int*)d_in[1];
    const float* ew   = (const float*)d_in[2];
    const float* emb  = (const float*)d_in[3];
    const float* Wl[4] = {(const float*)d_in[4],  (const float*)d_in[8],
                          (const float*)d_in[12], (const float*)d_in[16]};
    const float* Wr[4] = {(const float*)d_in[5],  (const float*)d_in[9],
                          (const float*)d_in[13], (const float*)d_in[17]};
    const float* av[4] = {(const float*)d_in[6],  (const float*)d_in[10],
                          (const float*)d_in[14], (const float*)d_in[18]};
    const float* bv[4] = {(const float*)d_in[7],  (const float*)d_in[11],
                          (const float*)d_in[15], (const float*)d_in[19]};

    const int N = N_NODES, E = N_EDGES;
    const int* srcp = eidx;
    const int* dstp = eidx + E;

    // workspace layout
    float*  ws   = (float*)d_ws;
    float*  xbuf = ws;                                // N*128 f
    __half* xlh  = (__half*)(xbuf + (size_t)N * 128); // N*128 h (fp16 * XSCALE)
    float*  xr   = (float*)(xlh + (size_t)N * 128);   // N*128 f
    short*  wpk  = (short*)(xr + (size_t)N * 128);    // 4 layers x 65536 shorts
    int*    deg  = (int*)(wpk + 4 * 65536);           // N
    int*    off  = deg + N;                           // N+1
    int*    cur  = off + N + 1;                       // N
    int*    ssrc = cur + N;                           // E
    float*  sew  = (float*)(ssrc + E);                // E

    // ---- build dst-sorted CSR once
    zero_kernel<<<(N + 255) / 256, 256, 0, stream>>>(deg, N);
    count_deg_kernel<<<(E + 255) / 256, 256, 0, stream>>>(dstp, deg, E);
    scan_kernel<<<1, 1024, 0, stream>>>(deg, off, cur);
    scatter_kernel<<<(E + 255) / 256, 256, 0, stream>>>(srcp, dstp, ew, cur,
                                                        ssrc, sew, E);

    // ---- pack all W fragments (bf16 hi/lo) once
    pack_w_kernel<64><<<8,  256, 0, stream>>>(Wl[0], Wr[0], wpk);
    pack_w_kernel<128><<<16, 256, 0, stream>>>(Wl[1], Wr[1], wpk + 1 * 65536);
    pack_w_kernel<128><<<16, 256, 0, stream>>>(Wl[2], Wr[2], wpk + 2 * 65536);
    pack_w_kernel<128><<<16, 256, 0, stream>>>(Wl[3], Wr[3], wpk + 3 * 65536);

    // ---- layer 0 (K=64)
    mfma_transform_kernel<2, 4><<<MTILES, 256, 0, stream>>>(emb, wpk, xlh, xr);
    gat_node_kernel<0><<<(N * 64 + 255) / 256, 256, 0, stream>>>(
        xlh, xr, off, ssrc, sew, av[0], bv[0], xbuf, nullptr, N);

    // ---- layers 1,2 (K=128)
    for (int layer = 1; layer < 3; ++layer) {
        mfma_transform_kernel<4, 4><<<MTILES, 256, 0, stream>>>(
            xbuf, wpk + layer * 65536, xlh, xr);
        gat_node_kernel<0><<<(N * 64 + 255) / 256, 256, 0, stream>>>(
            xlh, xr, off, ssrc, sew, av[layer], bv[layer], xbuf, nullptr, N);
    }

    // ---- layer 3: xl for all nodes (MFMA, 8 l-tiles); xr only for pert rows
    mfma_transform_kernel<4, 2><<<MTILES, 128, 0, stream>>>(
        xbuf, wpk + 3 * 65536, xlh, xr);
    transform_r_pert_kernel<128, 8><<<BATCH / 8, 128, 0, stream>>>(
        xbuf, pert, Wr[3], xr);
    gat_node_kernel<1><<<(BATCH * 64 + 255) / 256, 256, 0, stream>>>(
        xlh, xr, off, ssrc, sew, av[3], bv[3], (float*)d_out, pert, BATCH);
}

// Round 14
// 240.971 us; speedup vs baseline: 1.2055x; 1.1632x over previous
//
#include <hip/hip_runtime.h>
#include <hip/hip_fp16.h>
#include <math.h>

#define N_NODES 20000
#define N_EDGES 400000
#define BATCH   4096
#define MTILES  (N_NODES / 16)   // 1250
#define XSCALE  1024.0f
#define XINV    (1.0f / 1024.0f)

typedef __attribute__((ext_vector_type(8))) short short8v;
typedef __attribute__((ext_vector_type(4))) float f32x4;

// ---- split fp32 into bf16 hi + bf16 lo (truncation; hi+lo ~ 16 mantissa bits)
__device__ __forceinline__ void bf16split(float v, short& h, short& l)
{
    unsigned u  = __float_as_uint(v);
    unsigned hu = u & 0xFFFF0000u;
    h = (short)(hu >> 16);
    const float lo = v - __uint_as_float(hu);
    l = (short)(__float_as_uint(lo) >> 16);
}

// ---- pack W[K][128] x2 (Wl,Wr) into B-fragments, bf16 hi/lo (once per layer).
// B-frag: lane&15 = N-col, k = (lane>>4)*8 + e. nt 0..7 = Wl, 8..15 = Wr.
template<int K>
__global__ __launch_bounds__(256)
void pack_w_kernel(const float* __restrict__ Wl, const float* __restrict__ Wr,
                   short* __restrict__ wpk)
{
    constexpr int KB = K / 32;
    const int t = blockIdx.x * 256 + threadIdx.x;
    if (t >= 16 * KB * 64) return;
    const int lane = t & 63;
    const int kb   = (t >> 6) % KB;
    const int nt   = t / (64 * KB);
    const float* W = (nt < 8) ? Wl : Wr;
    const int col  = (nt & 7) * 16 + (lane & 15);
    const int k0   = kb * 32 + (lane >> 4) * 8;
    short8v h, l;
#pragma unroll
    for (int e = 0; e < 8; ++e) {
        short hh, ll; bf16split(W[(size_t)(k0 + e) * 128 + col], hh, ll);
        h[e] = hh; l[e] = ll;
    }
    short* ob = wpk + ((size_t)(nt * KB + kb) * 2) * 512 + lane * 8;
    *(short8v*)ob         = h;
    *(short8v*)(ob + 512) = l;
}

// ---- MFMA transform with fused x packing (LDS stage, bf16 hi/lo in-reg,
// bf16x3 compensation). xl written as fp16 * XSCALE (L2-resident gathers);
// xr stays fp32. D layout (m89-verified): col = lane&15, row = (lane>>4)*4+reg.
template<int KB, int NWAVES>
__global__ __launch_bounds__(NWAVES * 64)
void mfma_transform_kernel(const float* __restrict__ x,
                           const short* __restrict__ wpk,
                           __half* __restrict__ xlh, float* __restrict__ xr)
{
    constexpr int K  = KB * 32;
    constexpr int KP = K + 4;
    __shared__ float xs[16 * KP];
    const int mtile = blockIdx.x;
    const int wid   = threadIdx.x >> 6;
    const int lane  = threadIdx.x & 63;

    {
        const float4* __restrict__ src = (const float4*)(x + (size_t)mtile * 16 * K);
        for (int idx = threadIdx.x; idx < 16 * K / 4; idx += NWAVES * 64) {
            const int row = idx / (K / 4), c4 = idx % (K / 4);
            *(float4*)(xs + row * KP + c4 * 4) = src[idx];
        }
    }
    __syncthreads();

    short8v ah[KB], al[KB];
    {
        const float* ab = xs + (lane & 15) * KP + (lane >> 4) * 8;
#pragma unroll
        for (int kb = 0; kb < KB; ++kb) {
            const float4 f0 = *(const float4*)(ab + kb * 32);
            const float4 f1 = *(const float4*)(ab + kb * 32 + 4);
            float tmp[8] = {f0.x, f0.y, f0.z, f0.w, f1.x, f1.y, f1.z, f1.w};
#pragma unroll
            for (int e = 0; e < 8; ++e) {
                short hh, ll; bf16split(tmp[e], hh, ll);
                ah[kb][e] = hh; al[kb][e] = ll;
            }
        }
    }

#pragma unroll
    for (int i = 0; i < 4; ++i) {
        const int nt = wid * 4 + i;
        const short* bb = wpk + ((size_t)nt * KB * 2) * 512 + lane * 8;
        f32x4 acc = {0.f, 0.f, 0.f, 0.f};
#pragma unroll
        for (int kb = 0; kb < KB; ++kb) {
            const short8v bh = *(const short8v*)(bb + (size_t)(kb * 2 + 0) * 512);
            const short8v bl = *(const short8v*)(bb + (size_t)(kb * 2 + 1) * 512);
            acc = __builtin_amdgcn_mfma_f32_16x16x32_bf16(ah[kb], bh, acc, 0, 0, 0);
            acc = __builtin_amdgcn_mfma_f32_16x16x32_bf16(ah[kb], bl, acc, 0, 0, 0);
            acc = __builtin_amdgcn_mfma_f32_16x16x32_bf16(al[kb], bh, acc, 0, 0, 0);
        }
        const int colb = (nt & 7) * 16 + (lane & 15);
        const int row0 = mtile * 16 + (lane >> 4) * 4;
        if (nt < 8) {
#pragma unroll
            for (int r = 0; r < 4; ++r)
                xlh[(size_t)(row0 + r) * 128 + colb] = __float2half(acc[r] * XSCALE);
        } else {
#pragma unroll
            for (int r = 0; r < 4; ++r)
                xr[(size_t)(row0 + r) * 128 + colb] = acc[r];
        }
    }
}

// ---- layer-3 xr only for the 4096 pert rows (scalar, register-pipelined)
template<int K, int G>
__global__ __launch_bounds__(128)
void transform_r_pert_kernel(const float* __restrict__ x,
                             const int* __restrict__ pert,
                             const float* __restrict__ W,
                             float* __restrict__ out)
{
    const int t  = threadIdx.x;
    const int i0 = blockIdx.x * G;

    const float* __restrict__ xrow[G];
#pragma unroll
    for (int g = 0; g < G; ++g)
        xrow[g] = x + (size_t)pert[i0 + g] * K;

    float acc[G];
#pragma unroll
    for (int g = 0; g < G; ++g) acc[g] = 0.f;

    float4 xA[G], xB[G];
    float wA[4], wB[4];

    auto loadc = [&](float4* xs, float* w, int k) {
#pragma unroll
        for (int g = 0; g < G; ++g)
            xs[g] = *(const float4*)(xrow[g] + k);
#pragma unroll
        for (int u = 0; u < 4; ++u) w[u] = W[(k + u) * 128 + t];
    };
    auto fmac = [&](const float4* xs, const float* w) {
#pragma unroll
        for (int g = 0; g < G; ++g) {
            acc[g] = fmaf(xs[g].x, w[0], acc[g]);
            acc[g] = fmaf(xs[g].y, w[1], acc[g]);
            acc[g] = fmaf(xs[g].z, w[2], acc[g]);
            acc[g] = fmaf(xs[g].w, w[3], acc[g]);
        }
    };

    loadc(xA, wA, 0);
    for (int k0 = 0; k0 < K; k0 += 8) {
        if (k0 + 4 < K) loadc(xB, wB, k0 + 4);
        fmac(xA, wA);
        if (k0 + 8 < K) loadc(xA, wA, k0 + 8);
        fmac(xB, wB);
    }

#pragma unroll
    for (int g = 0; g < G; ++g)
        out[(size_t)(i0 + g) * 128 + t] = acc[g];
}

// ---- zero an int buffer
__global__ __launch_bounds__(256)
void zero_kernel(int* __restrict__ p, int n)
{
    const int i = blockIdx.x * blockDim.x + threadIdx.x;
    if (i < n) p[i] = 0;
}

// ---- CSR build: count degrees
__global__ __launch_bounds__(256)
void count_deg_kernel(const int* __restrict__ dst, int* __restrict__ deg, int E)
{
    const int e = blockIdx.x * blockDim.x + threadIdx.x;
    if (e < E) atomicAdd(&deg[dst[e]], 1);
}

// ---- exclusive scan over 20000 degrees; one block, LDS-staged coalesced I/O.
#define CHUNK 20
#define SCAN_PAD (1024 * CHUNK)
__global__ __launch_bounds__(1024)
void scan_kernel(const int* __restrict__ deg, int* __restrict__ off,
                 int* __restrict__ cursor)
{
    __shared__ int xs[SCAN_PAD];
    __shared__ int sums[1024];
    const int t = threadIdx.x;
    for (int i = t; i < SCAN_PAD; i += 1024)
        xs[i] = (i < N_NODES) ? deg[i] : 0;
    __syncthreads();

    const int base = t * CHUNK;
    int local[CHUNK];
    int s = 0;
#pragma unroll
    for (int i = 0; i < CHUNK; ++i) {
        local[i] = s;
        s += xs[base + i];
    }
    sums[t] = s;
    __syncthreads();
    for (int d = 1; d < 1024; d <<= 1) {
        int v = (t >= d) ? sums[t - d] : 0;
        __syncthreads();
        sums[t] += v;
        __syncthreads();
    }
    const int prev = (t == 0) ? 0 : sums[t - 1];
#pragma unroll
    for (int i = 0; i < CHUNK; ++i)
        xs[base + i] = prev + local[i];
    __syncthreads();
    for (int i = t; i < N_NODES; i += 1024) {
        const int o = xs[i];
        off[i] = o;
        cursor[i] = o;
    }
    if (t == 1023) off[N_NODES] = sums[1023];
}

// ---- scatter edges into dst-sorted order
__global__ __launch_bounds__(256)
void scatter_kernel(const int* __restrict__ src, const int* __restrict__ dst,
                    const float* __restrict__ ew, int* __restrict__ cursor,
                    int* __restrict__ ssrc, float* __restrict__ sew, int E)
{
    const int e = blockIdx.x * blockDim.x + threadIdx.x;
    if (e >= E) return;
    const int p = atomicAdd(&cursor[dst[e]], 1);
    ssrc[p] = src[e];
    sew[p]  = ew[e];
}

// ---- fused GATv2 layer: one wave per dst node, 4 edge slots (round-6 layout:
// lane = q*16 + h*8 + j -> each lane owns 8 dims of ONE head; softmax chain
// computed once per head-half, merge = 10 quantities x 2 shuffle levels).
// xl is fp16 * XSCALE: 16B gather/lane/edge, L2-resident working set.
template<int LAST>
__global__ __launch_bounds__(256)
void gat_node_kernel(const __half* __restrict__ xl, const float* __restrict__ xr,
                     const int* __restrict__ off, const int* __restrict__ ssrc,
                     const float* __restrict__ sew, const float* __restrict__ a,
                     const float* __restrict__ b, float* __restrict__ xout,
                     const int* __restrict__ nodemap, int nnodes)
{
    const int widx = (int)((blockIdx.x * blockDim.x + threadIdx.x) >> 6);
    if (widx >= nnodes) return;
    const int node = LAST ? nodemap[widx] : widx;
    const int xrrow = widx;          // == node for !LAST; batch row for LAST
    const int lane = threadIdx.x & 63;
    const int q  = lane >> 4;        // edge slot (4)
    const int h  = (lane >> 3) & 1;  // head
    const int j  = lane & 7;
    const int cb = h * 64 + j * 8;   // this lane's 8 dims

    const float* xrp = xr + (size_t)xrrow * 128 + cb;
    const float4 rA = make_float4(xrp[0] * XSCALE, xrp[1] * XSCALE,
                                  xrp[2] * XSCALE, xrp[3] * XSCALE);
    const float4 rB = make_float4(xrp[4] * XSCALE, xrp[5] * XSCALE,
                                  xrp[6] * XSCALE, xrp[7] * XSCALE);
    const float4 aA = *(const float4*)(a + cb);
    const float4 aB = *(const float4*)(a + cb + 4);

    const int e0 = off[node], e1 = off[node + 1];

    float m = -1e30f, s = 0.f;
    float4 accA = {0,0,0,0}, accB = {0,0,0,0};

    auto ldh8 = [](const __half* p, float4& lo, float4& hi) {
        const uint4 raw = *(const uint4*)p;   // 8 fp16 in one dwordx4
        const float2 f0 = __half22float2(*(const __half2*)&raw.x);
        const float2 f1 = __half22float2(*(const __half2*)&raw.y);
        const float2 f2 = __half22float2(*(const __half2*)&raw.z);
        const float2 f3 = __half22float2(*(const __half2*)&raw.w);
        lo = make_float4(f0.x, f0.y, f1.x, f1.y);
        hi = make_float4(f2.x, f2.y, f3.x, f3.y);
    };
    auto lrelu4 = [](float4 v) {
        v.x = fmaxf(v.x, 0.2f * v.x); v.y = fmaxf(v.y, 0.2f * v.y);
        v.z = fmaxf(v.z, 0.2f * v.z); v.w = fmaxf(v.w, 0.2f * v.w);
        return v;
    };
    auto dot4 = [](float4 u, float4 v) {
        return fmaf(u.x, v.x, fmaf(u.y, v.y, fmaf(u.z, v.z, u.w * v.w)));
    };
    auto upd4 = [](float4 acc, float r, float c, float4 xv) {
        acc.x = fmaf(c, xv.x, acc.x * r); acc.y = fmaf(c, xv.y, acc.y * r);
        acc.z = fmaf(c, xv.z, acc.z * r); acc.w = fmaf(c, xv.w, acc.w * r);
        return acc;
    };

    for (int ebase = e0; ebase < e1; ebase += 4) {
        const int  ei    = ebase + q;
        const bool valid = ei < e1;
        const int  eic   = valid ? ei : (e1 - 1);
        const int  sn    = ssrc[eic];
        const float w    = valid ? sew[eic] : 0.f;
        float4 xA, xB;
        ldh8(xl + (size_t)sn * 128 + cb, xA, xB);   // scaled values

        const float4 vA = lrelu4(make_float4(xA.x + rA.x, xA.y + rA.y,
                                             xA.z + rA.z, xA.w + rA.w));
        const float4 vB = lrelu4(make_float4(xB.x + rB.x, xB.y + rB.y,
                                             xB.z + rB.z, xB.w + rB.w));
        float p = dot4(vA, aA) + dot4(vB, aB);
        p += __shfl_xor(p, 1, 64);
        p += __shfl_xor(p, 2, 64);
        p += __shfl_xor(p, 4, 64);       // per-8-lane group: own head's score
        p = valid ? p * XINV : -1e30f;   // exact unscale (lrelu pos-homogeneous)

        // online softmax (one native exp per edge per head-half)
        const float d   = p - m;
        const float t   = __expf(-fabsf(d));
        const bool  pos = d > 0.f;
        const float r   = pos ? t : 1.f;
        const float ex  = pos ? 1.f : t;
        m = pos ? p : m;
        const float c = ex * w;
        s = s * r + ex;
        accA = upd4(accA, r, c, xA);     // scaled message space
        accB = upd4(accB, r, c, xB);
    }

    // ---- merge the 4 slot states (across q: lane strides 16, 32)
    float mg = fmaxf(m, __shfl_xor(m, 16, 64));
    mg = fmaxf(mg, __shfl_xor(mg, 32, 64));
    const float rq = __expf(m - mg);     // 0 for dead slots
    float sq = s * rq;
    sq += __shfl_xor(sq, 16, 64);
    sq += __shfl_xor(sq, 32, 64);
    auto redsum2 = [](float v) {
        v += __shfl_xor(v, 16, 64);
        return v + __shfl_xor(v, 32, 64);
    };
    accA.x = redsum2(accA.x * rq); accA.y = redsum2(accA.y * rq);
    accA.z = redsum2(accA.z * rq); accA.w = redsum2(accA.w * rq);
    accB.x = redsum2(accB.x * rq); accB.y = redsum2(accB.y * rq);
    accB.z = redsum2(accB.z * rq); accB.w = redsum2(accB.w * rq);
    const float inv = XINV / (sq + 1e-16f);   // undo message scaling

    if (!LAST) {
        if (q == 0) {
            const float4 bA = *(const float4*)(b + cb);
            const float4 bB = *(const float4*)(b + cb + 4);
            float4 oA, oB;
            oA.x = accA.x * inv + bA.x; oA.x = oA.x > 0.f ? oA.x : expm1f(oA.x);
            oA.y = accA.y * inv + bA.y; oA.y = oA.y > 0.f ? oA.y : expm1f(oA.y);
            oA.z = accA.z * inv + bA.z; oA.z = oA.z > 0.f ? oA.z : expm1f(oA.z);
            oA.w = accA.w * inv + bA.w; oA.w = oA.w > 0.f ? oA.w : expm1f(oA.w);
            oB.x = accB.x * inv + bB.x; oB.x = oB.x > 0.f ? oB.x : expm1f(oB.x);
            oB.y = accB.y * inv + bB.y; oB.y = oB.y > 0.f ? oB.y : expm1f(oB.y);
            oB.z = accB.z * inv + bB.z; oB.z = oB.z > 0.f ? oB.z : expm1f(oB.z);
            oB.w = accB.w * inv + bB.w; oB.w = oB.w > 0.f ? oB.w : expm1f(oB.w);
            float* op = xout + (size_t)node * 128;
            *(float4*)(op + cb)     = oA;
            *(float4*)(op + cb + 4) = oB;
        }
    } else {
        // mean over heads: bring other head's normalized value via stride-8 shfl
        float oA[4] = {accA.x * inv, accA.y * inv, accA.z * inv, accA.w * inv};
        float oB[4] = {accB.x * inv, accB.y * inv, accB.z * inv, accB.w * inv};
        float pA[4], pB[4];
#pragma unroll
        for (int k = 0; k < 4; ++k) {
            pA[k] = __shfl_xor(oA[k], 8, 64);
            pB[k] = __shfl_xor(oB[k], 8, 64);
        }
        if (q == 0 && h == 0) {
            const float4 bA = *(const float4*)(b + j * 8);
            const float4 bB = *(const float4*)(b + j * 8 + 4);
            float* op = xout + (size_t)widx * 64 + j * 8;
            op[0] = 0.5f * (oA[0] + pA[0]) + bA.x;
            op[1] = 0.5f * (oA[1] + pA[1]) + bA.y;
            op[2] = 0.5f * (oA[2] + pA[2]) + bA.z;
            op[3] = 0.5f * (oA[3] + pA[3]) + bA.w;
            op[4] = 0.5f * (oB[0] + pB[0]) + bB.x;
            op[5] = 0.5f * (oB[1] + pB[1]) + bB.y;
            op[6] = 0.5f * (oB[2] + pB[2]) + bB.z;
            op[7] = 0.5f * (oB[3] + pB[3]) + bB.w;
        }
    }
}

extern "C" void kernel_launch(void* const* d_in, const int* in_sizes, int n_in,
                              void* d_out, int out_size, void* d_ws, size_t ws_size,
                              hipStream_t stream)
{
    const int*   pert = (const int*)d_in[0];
    const int*   eidx = (const int*)d_in[1];
    const float* ew   = (const float*)d_in[2];
    const float* emb  = (const float*)d_in[3];
    const float* Wl[4] = {(const float*)d_in[4],  (const float*)d_in[8],
                          (const float*)d_in[12], (const float*)d_in[16]};
    const float* Wr[4] = {(const float*)d_in[5],  (const float*)d_in[9],
                          (const float*)d_in[13], (const float*)d_in[17]};
    const float* av[4] = {(const float*)d_in[6],  (const float*)d_in[10],
                          (const float*)d_in[14], (const float*)d_in[18]};
    const float* bv[4] = {(const float*)d_in[7],  (const float*)d_in[11],
                          (const float*)d_in[15], (const float*)d_in[19]};

    const int N = N_NODES, E = N_EDGES;
    const int* srcp = eidx;
    const int* dstp = eidx + E;

    // workspace layout
    float*  ws   = (float*)d_ws;
    float*  xbuf = ws;                                // N*128 f
    __half* xlh  = (__half*)(xbuf + (size_t)N * 128); // N*128 h (fp16 * XSCALE)
    float*  xr   = (float*)(xlh + (size_t)N * 128);   // N*128 f
    short*  wpk  = (short*)(xr + (size_t)N * 128);    // 4 layers x 65536 shorts
    int*    deg  = (int*)(wpk + 4 * 65536);           // N
    int*    off  = deg + N;                           // N+1
    int*    cur  = off + N + 1;                       // N
    int*    ssrc = cur + N;                           // E
    float*  sew  = (float*)(ssrc + E);                // E

    // ---- build dst-sorted CSR once
    zero_kernel<<<(N + 255) / 256, 256, 0, stream>>>(deg, N);
    count_deg_kernel<<<(E + 255) / 256, 256, 0, stream>>>(dstp, deg, E);
    scan_kernel<<<1, 1024, 0, stream>>>(deg, off, cur);
    scatter_kernel<<<(E + 255) / 256, 256, 0, stream>>>(srcp, dstp, ew, cur,
                                                        ssrc, sew, E);

    // ---- pack all W fragments (bf16 hi/lo) once
    pack_w_kernel<64><<<8,  256, 0, stream>>>(Wl[0], Wr[0], wpk);
    pack_w_kernel<128><<<16, 256, 0, stream>>>(Wl[1], Wr[1], wpk + 1 * 65536);
    pack_w_kernel<128><<<16, 256, 0, stream>>>(Wl[2], Wr[2], wpk + 2 * 65536);
    pack_w_kernel<128><<<16, 256, 0, stream>>>(Wl[3], Wr[3], wpk + 3 * 65536);

    // ---- layer 0 (K=64)
    mfma_transform_kernel<2, 4><<<MTILES, 256, 0, stream>>>(emb, wpk, xlh, xr);
    gat_node_kernel<0><<<(N * 64 + 255) / 256, 256, 0, stream>>>(
        xlh, xr, off, ssrc, sew, av[0], bv[0], xbuf, nullptr, N);

    // ---- layers 1,2 (K=128)
    for (int layer = 1; layer < 3; ++layer) {
        mfma_transform_kernel<4, 4><<<MTILES, 256, 0, stream>>>(
            xbuf, wpk + layer * 65536, xlh, xr);
        gat_node_kernel<0><<<(N * 64 + 255) / 256, 256, 0, stream>>>(
            xlh, xr, off, ssrc, sew, av[layer], bv[layer], xbuf, nullptr, N);
    }

    // ---- layer 3: xl for all nodes (MFMA); xr only for pert rows
    mfma_transform_kernel<4, 2><<<MTILES, 128, 0, stream>>>(
        xbuf, wpk + 3 * 65536, xlh, xr);
    transform_r_pert_kernel<128, 8><<<BATCH / 8, 128, 0, stream>>>(
        xbuf, pert, Wr[3], xr);
    gat_node_kernel<1><<<(BATCH * 64 + 255) / 256, 256, 0, stream>>>(
        xlh, xr, off, ssrc, sew, av[3], bv[3], (float*)d_out, pert, BATCH);
}

// Round 15
// 237.929 us; speedup vs baseline: 1.2209x; 1.0128x over previous
//
#include <hip/hip_runtime.h>
#include <hip/hip_fp16.h>
#include <math.h>

#define N_NODES 20000
#define N_EDGES 400000
#define BATCH   4096
#define MTILES  (N_NODES / 16)   // 1250
#define XSCALE  1024.0f
#define XINV    (1.0f / 1024.0f)

typedef __attribute__((ext_vector_type(8))) short short8v;
typedef __attribute__((ext_vector_type(4))) float f32x4;

// ---- split fp32 into bf16 hi + bf16 lo (truncation; hi+lo ~ 16 mantissa bits)
__device__ __forceinline__ void bf16split(float v, short& h, short& l)
{
    unsigned u  = __float_as_uint(v);
    unsigned hu = u & 0xFFFF0000u;
    h = (short)(hu >> 16);
    const float lo = v - __uint_as_float(hu);
    l = (short)(__float_as_uint(lo) >> 16);
}

// ---- pack ALL 4 layers' W (Wl,Wr) into B-fragments in ONE dispatch.
// Per layer: nt 0..7 = Wl tiles, 8..15 = Wr tiles; B-frag lane&15 = N-col,
// k = (lane>>4)*8 + e. Flat thread ranges: L0 [0,2048) K=64; L1/2/3 4096 each.
__global__ __launch_bounds__(256)
void pack_w_all_kernel(const float* __restrict__ Wl0, const float* __restrict__ Wr0,
                       const float* __restrict__ Wl1, const float* __restrict__ Wr1,
                       const float* __restrict__ Wl2, const float* __restrict__ Wr2,
                       const float* __restrict__ Wl3, const float* __restrict__ Wr3,
                       short* __restrict__ wpk)
{
    const int t = blockIdx.x * 256 + threadIdx.x;
    if (t >= 14336) return;
    int layer, base, K;
    const float *Wl, *Wr;
    if (t < 2048)       { layer = 0; base = 0;     K = 64;  Wl = Wl0; Wr = Wr0; }
    else if (t < 6144)  { layer = 1; base = 2048;  K = 128; Wl = Wl1; Wr = Wr1; }
    else if (t < 10240) { layer = 2; base = 6144;  K = 128; Wl = Wl2; Wr = Wr2; }
    else                { layer = 3; base = 10240; K = 128; Wl = Wl3; Wr = Wr3; }
    const int KB   = K / 32;
    const int tt   = t - base;
    const int lane = tt & 63;
    const int kb   = (tt >> 6) % KB;
    const int nt   = tt / (64 * KB);
    const float* W = (nt < 8) ? Wl : Wr;
    const int col  = (nt & 7) * 16 + (lane & 15);
    const int k0   = kb * 32 + (lane >> 4) * 8;
    short8v h, l;
#pragma unroll
    for (int e = 0; e < 8; ++e) {
        short hh, ll; bf16split(W[(size_t)(k0 + e) * 128 + col], hh, ll);
        h[e] = hh; l[e] = ll;
    }
    short* ob = wpk + (size_t)layer * 65536
                    + ((size_t)(nt * KB + kb) * 2) * 512 + lane * 8;
    *(short8v*)ob         = h;
    *(short8v*)(ob + 512) = l;
}

// ---- MFMA transform with fused x packing (LDS stage, bf16 hi/lo in-reg,
// bf16x3 compensation). xl written as fp16 * XSCALE (L2-resident gathers);
// xr stays fp32. D layout (m89-verified): col = lane&15, row = (lane>>4)*4+reg.
template<int KB, int NWAVES>
__global__ __launch_bounds__(NWAVES * 64)
void mfma_transform_kernel(const float* __restrict__ x,
                           const short* __restrict__ wpk,
                           __half* __restrict__ xlh, float* __restrict__ xr)
{
    constexpr int K  = KB * 32;
    constexpr int KP = K + 4;
    __shared__ float xs[16 * KP];
    const int mtile = blockIdx.x;
    const int wid   = threadIdx.x >> 6;
    const int lane  = threadIdx.x & 63;

    {
        const float4* __restrict__ src = (const float4*)(x + (size_t)mtile * 16 * K);
        for (int idx = threadIdx.x; idx < 16 * K / 4; idx += NWAVES * 64) {
            const int row = idx / (K / 4), c4 = idx % (K / 4);
            *(float4*)(xs + row * KP + c4 * 4) = src[idx];
        }
    }
    __syncthreads();

    short8v ah[KB], al[KB];
    {
        const float* ab = xs + (lane & 15) * KP + (lane >> 4) * 8;
#pragma unroll
        for (int kb = 0; kb < KB; ++kb) {
            const float4 f0 = *(const float4*)(ab + kb * 32);
            const float4 f1 = *(const float4*)(ab + kb * 32 + 4);
            float tmp[8] = {f0.x, f0.y, f0.z, f0.w, f1.x, f1.y, f1.z, f1.w};
#pragma unroll
            for (int e = 0; e < 8; ++e) {
                short hh, ll; bf16split(tmp[e], hh, ll);
                ah[kb][e] = hh; al[kb][e] = ll;
            }
        }
    }

#pragma unroll
    for (int i = 0; i < 4; ++i) {
        const int nt = wid * 4 + i;
        const short* bb = wpk + ((size_t)nt * KB * 2) * 512 + lane * 8;
        f32x4 acc = {0.f, 0.f, 0.f, 0.f};
#pragma unroll
        for (int kb = 0; kb < KB; ++kb) {
            const short8v bh = *(const short8v*)(bb + (size_t)(kb * 2 + 0) * 512);
            const short8v bl = *(const short8v*)(bb + (size_t)(kb * 2 + 1) * 512);
            acc = __builtin_amdgcn_mfma_f32_16x16x32_bf16(ah[kb], bh, acc, 0, 0, 0);
            acc = __builtin_amdgcn_mfma_f32_16x16x32_bf16(ah[kb], bl, acc, 0, 0, 0);
            acc = __builtin_amdgcn_mfma_f32_16x16x32_bf16(al[kb], bh, acc, 0, 0, 0);
        }
        const int colb = (nt & 7) * 16 + (lane & 15);
        const int row0 = mtile * 16 + (lane >> 4) * 4;
        if (nt < 8) {
#pragma unroll
            for (int r = 0; r < 4; ++r)
                xlh[(size_t)(row0 + r) * 128 + colb] = __float2half(acc[r] * XSCALE);
        } else {
#pragma unroll
            for (int r = 0; r < 4; ++r)
                xr[(size_t)(row0 + r) * 128 + colb] = acc[r];
        }
    }
}

// ---- layer-3 xr only for the 4096 pert rows (scalar, register-pipelined)
template<int K, int G>
__global__ __launch_bounds__(128)
void transform_r_pert_kernel(const float* __restrict__ x,
                             const int* __restrict__ pert,
                             const float* __restrict__ W,
                             float* __restrict__ out)
{
    const int t  = threadIdx.x;
    const int i0 = blockIdx.x * G;

    const float* __restrict__ xrow[G];
#pragma unroll
    for (int g = 0; g < G; ++g)
        xrow[g] = x + (size_t)pert[i0 + g] * K;

    float acc[G];
#pragma unroll
    for (int g = 0; g < G; ++g) acc[g] = 0.f;

    float4 xA[G], xB[G];
    float wA[4], wB[4];

    auto loadc = [&](float4* xs, float* w, int k) {
#pragma unroll
        for (int g = 0; g < G; ++g)
            xs[g] = *(const float4*)(xrow[g] + k);
#pragma unroll
        for (int u = 0; u < 4; ++u) w[u] = W[(k + u) * 128 + t];
    };
    auto fmac = [&](const float4* xs, const float* w) {
#pragma unroll
        for (int g = 0; g < G; ++g) {
            acc[g] = fmaf(xs[g].x, w[0], acc[g]);
            acc[g] = fmaf(xs[g].y, w[1], acc[g]);
            acc[g] = fmaf(xs[g].z, w[2], acc[g]);
            acc[g] = fmaf(xs[g].w, w[3], acc[g]);
        }
    };

    loadc(xA, wA, 0);
    for (int k0 = 0; k0 < K; k0 += 8) {
        if (k0 + 4 < K) loadc(xB, wB, k0 + 4);
        fmac(xA, wA);
        if (k0 + 8 < K) loadc(xA, wA, k0 + 8);
        fmac(xB, wB);
    }

#pragma unroll
    for (int g = 0; g < G; ++g)
        out[(size_t)(i0 + g) * 128 + t] = acc[g];
}

// ---- zero an int buffer
__global__ __launch_bounds__(256)
void zero_kernel(int* __restrict__ p, int n)
{
    const int i = blockIdx.x * blockDim.x + threadIdx.x;
    if (i < n) p[i] = 0;
}

// ---- CSR build: count degrees
__global__ __launch_bounds__(256)
void count_deg_kernel(const int* __restrict__ dst, int* __restrict__ deg, int E)
{
    const int e = blockIdx.x * blockDim.x + threadIdx.x;
    if (e < E) atomicAdd(&deg[dst[e]], 1);
}

// ---- exclusive scan over 20000 degrees; one block, LDS-staged coalesced I/O.
#define CHUNK 20
#define SCAN_PAD (1024 * CHUNK)
__global__ __launch_bounds__(1024)
void scan_kernel(const int* __restrict__ deg, int* __restrict__ off,
                 int* __restrict__ cursor)
{
    __shared__ int xs[SCAN_PAD];
    __shared__ int sums[1024];
    const int t = threadIdx.x;
    for (int i = t; i < SCAN_PAD; i += 1024)
        xs[i] = (i < N_NODES) ? deg[i] : 0;
    __syncthreads();

    const int base = t * CHUNK;
    int local[CHUNK];
    int s = 0;
#pragma unroll
    for (int i = 0; i < CHUNK; ++i) {
        local[i] = s;
        s += xs[base + i];
    }
    sums[t] = s;
    __syncthreads();
    for (int d = 1; d < 1024; d <<= 1) {
        int v = (t >= d) ? sums[t - d] : 0;
        __syncthreads();
        sums[t] += v;
        __syncthreads();
    }
    const int prev = (t == 0) ? 0 : sums[t - 1];
#pragma unroll
    for (int i = 0; i < CHUNK; ++i)
        xs[base + i] = prev + local[i];
    __syncthreads();
    for (int i = t; i < N_NODES; i += 1024) {
        const int o = xs[i];
        off[i] = o;
        cursor[i] = o;
    }
    if (t == 1023) off[N_NODES] = sums[1023];
}

// ---- scatter edges into dst-sorted order
__global__ __launch_bounds__(256)
void scatter_kernel(const int* __restrict__ src, const int* __restrict__ dst,
                    const float* __restrict__ ew, int* __restrict__ cursor,
                    int* __restrict__ ssrc, float* __restrict__ sew, int E)
{
    const int e = blockIdx.x * blockDim.x + threadIdx.x;
    if (e >= E) return;
    const int p = atomicAdd(&cursor[dst[e]], 1);
    ssrc[p] = src[e];
    sew[p]  = ew[e];
}

// ---- fused GATv2 layer: one wave per dst node, 4 edge slots (lane =
// q*16 + h*8 + j). Edge loop is 1-deep software-pipelined: round r+1's
// ssrc/sew loads AND xl row gather issue before round r's compute, hiding
// the ~300cy L2 gather latency under the softmax/update VALU work.
// xl is fp16 * XSCALE: 16B gather/lane/edge, L2-resident working set.
template<int LAST>
__global__ __launch_bounds__(256)
void gat_node_kernel(const __half* __restrict__ xl, const float* __restrict__ xr,
                     const int* __restrict__ off, const int* __restrict__ ssrc,
                     const float* __restrict__ sew, const float* __restrict__ a,
                     const float* __restrict__ b, float* __restrict__ xout,
                     const int* __restrict__ nodemap, int nnodes)
{
    const int widx = (int)((blockIdx.x * blockDim.x + threadIdx.x) >> 6);
    if (widx >= nnodes) return;
    const int node = LAST ? nodemap[widx] : widx;
    const int xrrow = widx;          // == node for !LAST; batch row for LAST
    const int lane = threadIdx.x & 63;
    const int q  = lane >> 4;        // edge slot (4)
    const int h  = (lane >> 3) & 1;  // head
    const int j  = lane & 7;
    const int cb = h * 64 + j * 8;   // this lane's 8 dims

    const float* xrp = xr + (size_t)xrrow * 128 + cb;
    const float4 rA = make_float4(xrp[0] * XSCALE, xrp[1] * XSCALE,
                                  xrp[2] * XSCALE, xrp[3] * XSCALE);
    const float4 rB = make_float4(xrp[4] * XSCALE, xrp[5] * XSCALE,
                                  xrp[6] * XSCALE, xrp[7] * XSCALE);
    const float4 aA = *(const float4*)(a + cb);
    const float4 aB = *(const float4*)(a + cb + 4);

    const int e0 = off[node], e1 = off[node + 1];
    const int nr = (e1 - e0 + 3) >> 2;   // rounds

    float m = -1e30f, s = 0.f;
    float4 accA = {0,0,0,0}, accB = {0,0,0,0};

    auto ldh8 = [](const __half* p, float4& lo, float4& hi) {
        const uint4 raw = *(const uint4*)p;   // 8 fp16 in one dwordx4
        const float2 f0 = __half22float2(*(const __half2*)&raw.x);
        const float2 f1 = __half22float2(*(const __half2*)&raw.y);
        const float2 f2 = __half22float2(*(const __half2*)&raw.z);
        const float2 f3 = __half22float2(*(const __half2*)&raw.w);
        lo = make_float4(f0.x, f0.y, f1.x, f1.y);
        hi = make_float4(f2.x, f2.y, f3.x, f3.y);
    };
    auto lrelu4 = [](float4 v) {
        v.x = fmaxf(v.x, 0.2f * v.x); v.y = fmaxf(v.y, 0.2f * v.y);
        v.z = fmaxf(v.z, 0.2f * v.z); v.w = fmaxf(v.w, 0.2f * v.w);
        return v;
    };
    auto dot4 = [](float4 u, float4 v) {
        return fmaf(u.x, v.x, fmaf(u.y, v.y, fmaf(u.z, v.z, u.w * v.w)));
    };
    auto upd4 = [](float4 acc, float r, float c, float4 xv) {
        acc.x = fmaf(c, xv.x, acc.x * r); acc.y = fmaf(c, xv.y, acc.y * r);
        acc.z = fmaf(c, xv.z, acc.z * r); acc.w = fmaf(c, xv.w, acc.w * r);
        return acc;
    };
    auto lde = [&](int r, float& w, bool& valid, float4& xA, float4& xB) {
        const int ei  = e0 + r * 4 + q;
        valid = ei < e1;
        const int eic = valid ? ei : (e1 - 1);
        const int sn  = ssrc[eic];
        w = valid ? sew[eic] : 0.f;
        ldh8(xl + (size_t)sn * 128 + cb, xA, xB);
    };

    float w_c; bool v_c; float4 xA_c, xB_c;
    if (nr > 0) lde(0, w_c, v_c, xA_c, xB_c);

    for (int r = 0; r < nr; ++r) {
        float w_n; bool v_n; float4 xA_n, xB_n;
        if (r + 1 < nr) lde(r + 1, w_n, v_n, xA_n, xB_n);   // issue-early

        const float4 vA = lrelu4(make_float4(xA_c.x + rA.x, xA_c.y + rA.y,
                                             xA_c.z + rA.z, xA_c.w + rA.w));
        const float4 vB = lrelu4(make_float4(xB_c.x + rB.x, xB_c.y + rB.y,
                                             xB_c.z + rB.z, xB_c.w + rB.w));
        float p = dot4(vA, aA) + dot4(vB, aB);
        p += __shfl_xor(p, 1, 64);
        p += __shfl_xor(p, 2, 64);
        p += __shfl_xor(p, 4, 64);       // per-8-lane group: own head's score
        p = v_c ? p * XINV : -1e30f;     // exact unscale (lrelu pos-homogeneous)

        const float d   = p - m;
        const float t   = __expf(-fabsf(d));
        const bool  pos = d > 0.f;
        const float rr  = pos ? t : 1.f;
        const float ex  = pos ? 1.f : t;
        m = pos ? p : m;
        const float c = ex * w_c;
        s = s * rr + ex;
        accA = upd4(accA, rr, c, xA_c);  // scaled message space
        accB = upd4(accB, rr, c, xB_c);

        w_c = w_n; v_c = v_n; xA_c = xA_n; xB_c = xB_n;
    }

    // ---- merge the 4 slot states (across q: lane strides 16, 32)
    float mg = fmaxf(m, __shfl_xor(m, 16, 64));
    mg = fmaxf(mg, __shfl_xor(mg, 32, 64));
    const float rq = __expf(m - mg);     // 0 for dead slots
    float sq = s * rq;
    sq += __shfl_xor(sq, 16, 64);
    sq += __shfl_xor(sq, 32, 64);
    auto redsum2 = [](float v) {
        v += __shfl_xor(v, 16, 64);
        return v + __shfl_xor(v, 32, 64);
    };
    accA.x = redsum2(accA.x * rq); accA.y = redsum2(accA.y * rq);
    accA.z = redsum2(accA.z * rq); accA.w = redsum2(accA.w * rq);
    accB.x = redsum2(accB.x * rq); accB.y = redsum2(accB.y * rq);
    accB.z = redsum2(accB.z * rq); accB.w = redsum2(accB.w * rq);
    const float inv = XINV / (sq + 1e-16f);   // undo message scaling

    if (!LAST) {
        if (q == 0) {
            const float4 bA = *(const float4*)(b + cb);
            const float4 bB = *(const float4*)(b + cb + 4);
            float4 oA, oB;
            oA.x = accA.x * inv + bA.x; oA.x = oA.x > 0.f ? oA.x : expm1f(oA.x);
            oA.y = accA.y * inv + bA.y; oA.y = oA.y > 0.f ? oA.y : expm1f(oA.y);
            oA.z = accA.z * inv + bA.z; oA.z = oA.z > 0.f ? oA.z : expm1f(oA.z);
            oA.w = accA.w * inv + bA.w; oA.w = oA.w > 0.f ? oA.w : expm1f(oA.w);
            oB.x = accB.x * inv + bB.x; oB.x = oB.x > 0.f ? oB.x : expm1f(oB.x);
            oB.y = accB.y * inv + bB.y; oB.y = oB.y > 0.f ? oB.y : expm1f(oB.y);
            oB.z = accB.z * inv + bB.z; oB.z = oB.z > 0.f ? oB.z : expm1f(oB.z);
            oB.w = accB.w * inv + bB.w; oB.w = oB.w > 0.f ? oB.w : expm1f(oB.w);
            float* op = xout + (size_t)node * 128;
            *(float4*)(op + cb)     = oA;
            *(float4*)(op + cb + 4) = oB;
        }
    } else {
        // mean over heads: bring other head's normalized value via stride-8 shfl
        float oA[4] = {accA.x * inv, accA.y * inv, accA.z * inv, accA.w * inv};
        float oB[4] = {accB.x * inv, accB.y * inv, accB.z * inv, accB.w * inv};
        float pA[4], pB[4];
#pragma unroll
        for (int k = 0; k < 4; ++k) {
            pA[k] = __shfl_xor(oA[k], 8, 64);
            pB[k] = __shfl_xor(oB[k], 8, 64);
        }
        if (q == 0 && h == 0) {
            const float4 bA = *(const float4*)(b + j * 8);
            const float4 bB = *(const float4*)(b + j * 8 + 4);
            float* op = xout + (size_t)widx * 64 + j * 8;
            op[0] = 0.5f * (oA[0] + pA[0]) + bA.x;
            op[1] = 0.5f * (oA[1] + pA[1]) + bA.y;
            op[2] = 0.5f * (oA[2] + pA[2]) + bA.z;
            op[3] = 0.5f * (oA[3] + pA[3]) + bA.w;
            op[4] = 0.5f * (oB[0] + pB[0]) + bB.x;
            op[5] = 0.5f * (oB[1] + pB[1]) + bB.y;
            op[6] = 0.5f * (oB[2] + pB[2]) + bB.z;
            op[7] = 0.5f * (oB[3] + pB[3]) + bB.w;
        }
    }
}

extern "C" void kernel_launch(void* const* d_in, const int* in_sizes, int n_in,
                              void* d_out, int out_size, void* d_ws, size_t ws_size,
                              hipStream_t stream)
{
    const int*   pert = (const int*)d_in[0];
    const int*   eidx = (const int*)d_in[1];
    const float* ew   = (const float*)d_in[2];
    const float* emb  = (const float*)d_in[3];
    const float* Wl[4] = {(const float*)d_in[4],  (const float*)d_in[8],
                          (const float*)d_in[12], (const float*)d_in[16]};
    const float* Wr[4] = {(const float*)d_in[5],  (const float*)d_in[9],
                          (const float*)d_in[13], (const float*)d_in[17]};
    const float* av[4] = {(const float*)d_in[6],  (const float*)d_in[10],
                          (const float*)d_in[14], (const float*)d_in[18]};
    const float* bv[4] = {(const float*)d_in[7],  (const float*)d_in[11],
                          (const float*)d_in[15], (const float*)d_in[19]};

    const int N = N_NODES, E = N_EDGES;
    const int* srcp = eidx;
    const int* dstp = eidx + E;

    // workspace layout
    float*  ws   = (float*)d_ws;
    float*  xbuf = ws;                                // N*128 f
    __half* xlh  = (__half*)(xbuf + (size_t)N * 128); // N*128 h (fp16 * XSCALE)
    float*  xr   = (float*)(xlh + (size_t)N * 128);   // N*128 f
    short*  wpk  = (short*)(xr + (size_t)N * 128);    // 4 layers x 65536 shorts
    int*    deg  = (int*)(wpk + 4 * 65536);           // N
    int*    off  = deg + N;                           // N+1
    int*    cur  = off + N + 1;                       // N
    int*    ssrc = cur + N;                           // E
    float*  sew  = (float*)(ssrc + E);                // E

    // ---- build dst-sorted CSR once
    zero_kernel<<<(N + 255) / 256, 256, 0, stream>>>(deg, N);
    count_deg_kernel<<<(E + 255) / 256, 256, 0, stream>>>(dstp, deg, E);
    scan_kernel<<<1, 1024, 0, stream>>>(deg, off, cur);
    scatter_kernel<<<(E + 255) / 256, 256, 0, stream>>>(srcp, dstp, ew, cur,
                                                        ssrc, sew, E);

    // ---- pack all W fragments (bf16 hi/lo) in one dispatch
    pack_w_all_kernel<<<56, 256, 0, stream>>>(Wl[0], Wr[0], Wl[1], Wr[1],
                                              Wl[2], Wr[2], Wl[3], Wr[3], wpk);

    // ---- layer 0 (K=64)
    mfma_transform_kernel<2, 4><<<MTILES, 256, 0, stream>>>(emb, wpk, xlh, xr);
    gat_node_kernel<0><<<(N * 64 + 255) / 256, 256, 0, stream>>>(
        xlh, xr, off, ssrc, sew, av[0], bv[0], xbuf, nullptr, N);

    // ---- layers 1,2 (K=128)
    for (int layer = 1; layer < 3; ++layer) {
        mfma_transform_kernel<4, 4><<<MTILES, 256, 0, stream>>>(
            xbuf, wpk + layer * 65536, xlh, xr);
        gat_node_kernel<0><<<(N * 64 + 255) / 256, 256, 0, stream>>>(
            xlh, xr, off, ssrc, sew, av[layer], bv[layer], xbuf, nullptr, N);
    }

    // ---- layer 3: xl for all nodes (MFMA); xr only for pert rows
    mfma_transform_kernel<4, 2><<<MTILES, 128, 0, stream>>>(
        xbuf, wpk + 3 * 65536, xlh, xr);
    transform_r_pert_kernel<128, 8><<<BATCH / 8, 128, 0, stream>>>(
        xbuf, pert, Wr[3], xr);
    gat_node_kernel<1><<<(BATCH * 64 + 255) / 256, 256, 0, stream>>>(
        xlh, xr, off, ssrc, sew, av[3], bv[3], (float*)d_out, pert, BATCH);
}

// Round 16
// 234.639 us; speedup vs baseline: 1.2380x; 1.0140x over previous
//
#include <hip/hip_runtime.h>
#include <hip/hip_fp16.h>
#include <math.h>

#define N_NODES 20000
#define N_EDGES 400000
#define BATCH   4096
#define MTILES  (N_NODES / 16)   // 1250
#define XSCALE  1024.0f
#define XINV    (1.0f / 1024.0f)

typedef __attribute__((ext_vector_type(8))) short short8v;
typedef __attribute__((ext_vector_type(4))) float f32x4;

// ---- split fp32 into bf16 hi + bf16 lo (truncation; hi+lo ~ 16 mantissa bits)
__device__ __forceinline__ void bf16split(float v, short& h, short& l)
{
    unsigned u  = __float_as_uint(v);
    unsigned hu = u & 0xFFFF0000u;
    h = (short)(hu >> 16);
    const float lo = v - __uint_as_float(hu);
    l = (short)(__float_as_uint(lo) >> 16);
}

// ---- prep: zero deg (t < N_NODES) + pack ALL 4 layers' W into B-fragments
// (t in [N_NODES, N_NODES+14336)). One dispatch replaces two.
__global__ __launch_bounds__(256)
void prep_kernel(int* __restrict__ deg,
                 const float* __restrict__ Wl0, const float* __restrict__ Wr0,
                 const float* __restrict__ Wl1, const float* __restrict__ Wr1,
                 const float* __restrict__ Wl2, const float* __restrict__ Wr2,
                 const float* __restrict__ Wl3, const float* __restrict__ Wr3,
                 short* __restrict__ wpk)
{
    const int t = blockIdx.x * 256 + threadIdx.x;
    if (t < N_NODES) { deg[t] = 0; return; }
    const int tp = t - N_NODES;
    if (tp >= 14336) return;
    int layer, base, K;
    const float *Wl, *Wr;
    if (tp < 2048)       { layer = 0; base = 0;     K = 64;  Wl = Wl0; Wr = Wr0; }
    else if (tp < 6144)  { layer = 1; base = 2048;  K = 128; Wl = Wl1; Wr = Wr1; }
    else if (tp < 10240) { layer = 2; base = 6144;  K = 128; Wl = Wl2; Wr = Wr2; }
    else                 { layer = 3; base = 10240; K = 128; Wl = Wl3; Wr = Wr3; }
    const int KB   = K / 32;
    const int tt   = tp - base;
    const int lane = tt & 63;
    const int kb   = (tt >> 6) % KB;
    const int nt   = tt / (64 * KB);
    const float* W = (nt < 8) ? Wl : Wr;
    const int col  = (nt & 7) * 16 + (lane & 15);
    const int k0   = kb * 32 + (lane >> 4) * 8;
    short8v h, l;
#pragma unroll
    for (int e = 0; e < 8; ++e) {
        short hh, ll; bf16split(W[(size_t)(k0 + e) * 128 + col], hh, ll);
        h[e] = hh; l[e] = ll;
    }
    short* ob = wpk + (size_t)layer * 65536
                    + ((size_t)(nt * KB + kb) * 2) * 512 + lane * 8;
    *(short8v*)ob         = h;
    *(short8v*)(ob + 512) = l;
}

// ---- MFMA transform with fused x packing (LDS stage, bf16 hi/lo in-reg,
// bf16x3 compensation). xl written as fp16 * XSCALE (L2-resident gathers);
// xr stays fp32. D layout (m89-verified): col = lane&15, row = (lane>>4)*4+reg.
template<int KB, int NWAVES>
__global__ __launch_bounds__(NWAVES * 64)
void mfma_transform_kernel(const float* __restrict__ x,
                           const short* __restrict__ wpk,
                           __half* __restrict__ xlh, float* __restrict__ xr)
{
    constexpr int K  = KB * 32;
    constexpr int KP = K + 4;
    __shared__ float xs[16 * KP];
    const int mtile = blockIdx.x;
    const int wid   = threadIdx.x >> 6;
    const int lane  = threadIdx.x & 63;

    {
        const float4* __restrict__ src = (const float4*)(x + (size_t)mtile * 16 * K);
        for (int idx = threadIdx.x; idx < 16 * K / 4; idx += NWAVES * 64) {
            const int row = idx / (K / 4), c4 = idx % (K / 4);
            *(float4*)(xs + row * KP + c4 * 4) = src[idx];
        }
    }
    __syncthreads();

    short8v ah[KB], al[KB];
    {
        const float* ab = xs + (lane & 15) * KP + (lane >> 4) * 8;
#pragma unroll
        for (int kb = 0; kb < KB; ++kb) {
            const float4 f0 = *(const float4*)(ab + kb * 32);
            const float4 f1 = *(const float4*)(ab + kb * 32 + 4);
            float tmp[8] = {f0.x, f0.y, f0.z, f0.w, f1.x, f1.y, f1.z, f1.w};
#pragma unroll
            for (int e = 0; e < 8; ++e) {
                short hh, ll; bf16split(tmp[e], hh, ll);
                ah[kb][e] = hh; al[kb][e] = ll;
            }
        }
    }

#pragma unroll
    for (int i = 0; i < 4; ++i) {
        const int nt = wid * 4 + i;
        const short* bb = wpk + ((size_t)nt * KB * 2) * 512 + lane * 8;
        f32x4 acc = {0.f, 0.f, 0.f, 0.f};
#pragma unroll
        for (int kb = 0; kb < KB; ++kb) {
            const short8v bh = *(const short8v*)(bb + (size_t)(kb * 2 + 0) * 512);
            const short8v bl = *(const short8v*)(bb + (size_t)(kb * 2 + 1) * 512);
            acc = __builtin_amdgcn_mfma_f32_16x16x32_bf16(ah[kb], bh, acc, 0, 0, 0);
            acc = __builtin_amdgcn_mfma_f32_16x16x32_bf16(ah[kb], bl, acc, 0, 0, 0);
            acc = __builtin_amdgcn_mfma_f32_16x16x32_bf16(al[kb], bh, acc, 0, 0, 0);
        }
        const int colb = (nt & 7) * 16 + (lane & 15);
        const int row0 = mtile * 16 + (lane >> 4) * 4;
        if (nt < 8) {
#pragma unroll
            for (int r = 0; r < 4; ++r)
                xlh[(size_t)(row0 + r) * 128 + colb] = __float2half(acc[r] * XSCALE);
        } else {
#pragma unroll
            for (int r = 0; r < 4; ++r)
                xr[(size_t)(row0 + r) * 128 + colb] = acc[r];
        }
    }
}

// ---- layer 3 fused: blocks [0,MTILES) = MFMA xl transform (2 waves, xl only);
// blocks [MTILES, MTILES+BATCH/8) = xr for pert rows (scalar pipelined).
__global__ __launch_bounds__(128)
void l3_fused_kernel(const float* __restrict__ x, const short* __restrict__ wpk,
                     __half* __restrict__ xlh,
                     const int* __restrict__ pert, const float* __restrict__ Wr3,
                     float* __restrict__ xr)
{
    constexpr int K  = 128;
    constexpr int KP = K + 4;
    __shared__ float xs[16 * KP];

    if (blockIdx.x < MTILES) {
        const int mtile = blockIdx.x;
        const int wid   = threadIdx.x >> 6;
        const int lane  = threadIdx.x & 63;
        {
            const float4* __restrict__ src = (const float4*)(x + (size_t)mtile * 16 * K);
            for (int idx = threadIdx.x; idx < 16 * K / 4; idx += 128) {
                const int row = idx / (K / 4), c4 = idx % (K / 4);
                *(float4*)(xs + row * KP + c4 * 4) = src[idx];
            }
        }
        __syncthreads();

        short8v ah[4], al[4];
        {
            const float* ab = xs + (lane & 15) * KP + (lane >> 4) * 8;
#pragma unroll
            for (int kb = 0; kb < 4; ++kb) {
                const float4 f0 = *(const float4*)(ab + kb * 32);
                const float4 f1 = *(const float4*)(ab + kb * 32 + 4);
                float tmp[8] = {f0.x, f0.y, f0.z, f0.w, f1.x, f1.y, f1.z, f1.w};
#pragma unroll
                for (int e = 0; e < 8; ++e) {
                    short hh, ll; bf16split(tmp[e], hh, ll);
                    ah[kb][e] = hh; al[kb][e] = ll;
                }
            }
        }
#pragma unroll
        for (int i = 0; i < 4; ++i) {
            const int nt = wid * 4 + i;       // 0..7: xl tiles only
            const short* bb = wpk + ((size_t)nt * 4 * 2) * 512 + lane * 8;
            f32x4 acc = {0.f, 0.f, 0.f, 0.f};
#pragma unroll
            for (int kb = 0; kb < 4; ++kb) {
                const short8v bh = *(const short8v*)(bb + (size_t)(kb * 2 + 0) * 512);
                const short8v bl = *(const short8v*)(bb + (size_t)(kb * 2 + 1) * 512);
                acc = __builtin_amdgcn_mfma_f32_16x16x32_bf16(ah[kb], bh, acc, 0, 0, 0);
                acc = __builtin_amdgcn_mfma_f32_16x16x32_bf16(ah[kb], bl, acc, 0, 0, 0);
                acc = __builtin_amdgcn_mfma_f32_16x16x32_bf16(al[kb], bh, acc, 0, 0, 0);
            }
            const int colb = (nt & 7) * 16 + (lane & 15);
            const int row0 = mtile * 16 + (lane >> 4) * 4;
#pragma unroll
            for (int r = 0; r < 4; ++r)
                xlh[(size_t)(row0 + r) * 128 + colb] = __float2half(acc[r] * XSCALE);
        }
    } else {
        // ---- xr for pert rows
        constexpr int G = 8;
        const int t  = threadIdx.x;
        const int i0 = (blockIdx.x - MTILES) * G;

        const float* __restrict__ xrow[G];
#pragma unroll
        for (int g = 0; g < G; ++g)
            xrow[g] = x + (size_t)pert[i0 + g] * K;

        float acc[G];
#pragma unroll
        for (int g = 0; g < G; ++g) acc[g] = 0.f;

        float4 xA[G], xB[G];
        float wA[4], wB[4];

        auto loadc = [&](float4* xv, float* w, int k) {
#pragma unroll
            for (int g = 0; g < G; ++g)
                xv[g] = *(const float4*)(xrow[g] + k);
#pragma unroll
            for (int u = 0; u < 4; ++u) w[u] = Wr3[(k + u) * 128 + t];
        };
        auto fmac = [&](const float4* xv, const float* w) {
#pragma unroll
            for (int g = 0; g < G; ++g) {
                acc[g] = fmaf(xv[g].x, w[0], acc[g]);
                acc[g] = fmaf(xv[g].y, w[1], acc[g]);
                acc[g] = fmaf(xv[g].z, w[2], acc[g]);
                acc[g] = fmaf(xv[g].w, w[3], acc[g]);
            }
        };

        loadc(xA, wA, 0);
        for (int k0 = 0; k0 < K; k0 += 8) {
            if (k0 + 4 < K) loadc(xB, wB, k0 + 4);
            fmac(xA, wA);
            if (k0 + 8 < K) loadc(xA, wA, k0 + 8);
            fmac(xB, wB);
        }
#pragma unroll
        for (int g = 0; g < G; ++g)
            xr[(size_t)(i0 + g) * 128 + t] = acc[g];
    }
}

// ---- CSR build: count degrees
__global__ __launch_bounds__(256)
void count_deg_kernel(const int* __restrict__ dst, int* __restrict__ deg, int E)
{
    const int e = blockIdx.x * blockDim.x + threadIdx.x;
    if (e < E) atomicAdd(&deg[dst[e]], 1);
}

// ---- exclusive scan over 20000 degrees; one block, LDS-staged coalesced I/O.
#define CHUNK 20
#define SCAN_PAD (1024 * CHUNK)
__global__ __launch_bounds__(1024)
void scan_kernel(const int* __restrict__ deg, int* __restrict__ off,
                 int* __restrict__ cursor)
{
    __shared__ int xs[SCAN_PAD];
    __shared__ int sums[1024];
    const int t = threadIdx.x;
    for (int i = t; i < SCAN_PAD; i += 1024)
        xs[i] = (i < N_NODES) ? deg[i] : 0;
    __syncthreads();

    const int base = t * CHUNK;
    int local[CHUNK];
    int s = 0;
#pragma unroll
    for (int i = 0; i < CHUNK; ++i) {
        local[i] = s;
        s += xs[base + i];
    }
    sums[t] = s;
    __syncthreads();
    for (int d = 1; d < 1024; d <<= 1) {
        int v = (t >= d) ? sums[t - d] : 0;
        __syncthreads();
        sums[t] += v;
        __syncthreads();
    }
    const int prev = (t == 0) ? 0 : sums[t - 1];
#pragma unroll
    for (int i = 0; i < CHUNK; ++i)
        xs[base + i] = prev + local[i];
    __syncthreads();
    for (int i = t; i < N_NODES; i += 1024) {
        const int o = xs[i];
        off[i] = o;
        cursor[i] = o;
    }
    if (t == 1023) off[N_NODES] = sums[1023];
}

// ---- scatter edges into dst-sorted order
__global__ __launch_bounds__(256)
void scatter_kernel(const int* __restrict__ src, const int* __restrict__ dst,
                    const float* __restrict__ ew, int* __restrict__ cursor,
                    int* __restrict__ ssrc, float* __restrict__ sew, int E)
{
    const int e = blockIdx.x * blockDim.x + threadIdx.x;
    if (e >= E) return;
    const int p = atomicAdd(&cursor[dst[e]], 1);
    ssrc[p] = src[e];
    sew[p]  = ew[e];
}

// ---- fused GATv2 layer: one wave per dst node, 4 edge slots (lane =
// q*16 + h*8 + j). Defer-max online softmax (T13): keep reference m fixed
// unless a score exceeds it by >8 (ex <= e^8, fp32-safe); fast path skips the
// rescale muls entirely. Slot-merge epilogue is exact for any reference m.
// xl is fp16 * XSCALE: 16B gather/lane/edge, L2-resident working set.
template<int LAST>
__global__ __launch_bounds__(256)
void gat_node_kernel(const __half* __restrict__ xl, const float* __restrict__ xr,
                     const int* __restrict__ off, const int* __restrict__ ssrc,
                     const float* __restrict__ sew, const float* __restrict__ a,
                     const float* __restrict__ b, float* __restrict__ xout,
                     const int* __restrict__ nodemap, int nnodes)
{
    const int widx = (int)((blockIdx.x * blockDim.x + threadIdx.x) >> 6);
    if (widx >= nnodes) return;
    const int node = LAST ? nodemap[widx] : widx;
    const int xrrow = widx;          // == node for !LAST; batch row for LAST
    const int lane = threadIdx.x & 63;
    const int q  = lane >> 4;        // edge slot (4)
    const int h  = (lane >> 3) & 1;  // head
    const int j  = lane & 7;
    const int cb = h * 64 + j * 8;   // this lane's 8 dims

    const float* xrp = xr + (size_t)xrrow * 128 + cb;
    const float4 rA = make_float4(xrp[0] * XSCALE, xrp[1] * XSCALE,
                                  xrp[2] * XSCALE, xrp[3] * XSCALE);
    const float4 rB = make_float4(xrp[4] * XSCALE, xrp[5] * XSCALE,
                                  xrp[6] * XSCALE, xrp[7] * XSCALE);
    const float4 aA = *(const float4*)(a + cb);
    const float4 aB = *(const float4*)(a + cb + 4);

    const int e0 = off[node], e1 = off[node + 1];
    const int nr = (e1 - e0 + 3) >> 2;   // rounds

    float m = -1e30f, s = 0.f;
    float4 accA = {0,0,0,0}, accB = {0,0,0,0};

    auto ldh8 = [](const __half* p, float4& lo, float4& hi) {
        const uint4 raw = *(const uint4*)p;   // 8 fp16 in one dwordx4
        const float2 f0 = __half22float2(*(const __half2*)&raw.x);
        const float2 f1 = __half22float2(*(const __half2*)&raw.y);
        const float2 f2 = __half22float2(*(const __half2*)&raw.z);
        const float2 f3 = __half22float2(*(const __half2*)&raw.w);
        lo = make_float4(f0.x, f0.y, f1.x, f1.y);
        hi = make_float4(f2.x, f2.y, f3.x, f3.y);
    };
    auto lrelu4 = [](float4 v) {
        v.x = fmaxf(v.x, 0.2f * v.x); v.y = fmaxf(v.y, 0.2f * v.y);
        v.z = fmaxf(v.z, 0.2f * v.z); v.w = fmaxf(v.w, 0.2f * v.w);
        return v;
    };
    auto dot4 = [](float4 u, float4 v) {
        return fmaf(u.x, v.x, fmaf(u.y, v.y, fmaf(u.z, v.z, u.w * v.w)));
    };
    auto upd4 = [](float4 acc, float r, float c, float4 xv) {
        acc.x = fmaf(c, xv.x, acc.x * r); acc.y = fmaf(c, xv.y, acc.y * r);
        acc.z = fmaf(c, xv.z, acc.z * r); acc.w = fmaf(c, xv.w, acc.w * r);
        return acc;
    };
    auto fma4 = [](float4 acc, float c, float4 xv) {
        acc.x = fmaf(c, xv.x, acc.x); acc.y = fmaf(c, xv.y, acc.y);
        acc.z = fmaf(c, xv.z, acc.z); acc.w = fmaf(c, xv.w, acc.w);
        return acc;
    };
    auto lde = [&](int r, float& w, bool& valid, float4& xA, float4& xB) {
        const int ei  = e0 + r * 4 + q;
        valid = ei < e1;
        const int eic = valid ? ei : (e1 - 1);
        const int sn  = ssrc[eic];
        w = valid ? sew[eic] : 0.f;
        ldh8(xl + (size_t)sn * 128 + cb, xA, xB);
    };

    float w_c; bool v_c; float4 xA_c, xB_c;
    if (nr > 0) lde(0, w_c, v_c, xA_c, xB_c);

    for (int r = 0; r < nr; ++r) {
        float w_n; bool v_n; float4 xA_n, xB_n;
        if (r + 1 < nr) lde(r + 1, w_n, v_n, xA_n, xB_n);   // issue-early

        const float4 vA = lrelu4(make_float4(xA_c.x + rA.x, xA_c.y + rA.y,
                                             xA_c.z + rA.z, xA_c.w + rA.w));
        const float4 vB = lrelu4(make_float4(xB_c.x + rB.x, xB_c.y + rB.y,
                                             xB_c.z + rB.z, xB_c.w + rB.w));
        float p = dot4(vA, aA) + dot4(vB, aB);
        p += __shfl_xor(p, 1, 64);
        p += __shfl_xor(p, 2, 64);
        p += __shfl_xor(p, 4, 64);       // per-8-lane group: own head's score
        p = v_c ? p * XINV : -1e30f;     // exact unscale (lrelu pos-homogeneous)

        const float d = p - m;           // group-uniform
        if (__any(d > 8.f)) {
            // slow path (rare: round 0 + large max jumps): full online update
            const float t   = __expf(-fabsf(d));
            const bool  pos = d > 0.f;
            const float rr  = pos ? t : 1.f;
            const float ex  = pos ? 1.f : t;
            m = pos ? p : m;
            const float c = ex * w_c;
            s = s * rr + ex;
            accA = upd4(accA, rr, c, xA_c);
            accB = upd4(accB, rr, c, xB_c);
        } else {
            // fast path: d <= 8 for every group -> no rescale needed
            const float ex = __expf(d);
            const float c  = ex * w_c;
            s += ex;
            accA = fma4(accA, c, xA_c);
            accB = fma4(accB, c, xB_c);
        }

        w_c = w_n; v_c = v_n; xA_c = xA_n; xB_c = xB_n;
    }

    // ---- merge the 4 slot states (across q: lane strides 16, 32)
    float mg = fmaxf(m, __shfl_xor(m, 16, 64));
    mg = fmaxf(mg, __shfl_xor(mg, 32, 64));
    const float rq = __expf(m - mg);     // 0 for dead slots
    float sq = s * rq;
    sq += __shfl_xor(sq, 16, 64);
    sq += __shfl_xor(sq, 32, 64);
    auto redsum2 = [](float v) {
        v += __shfl_xor(v, 16, 64);
        return v + __shfl_xor(v, 32, 64);
    };
    accA.x = redsum2(accA.x * rq); accA.y = redsum2(accA.y * rq);
    accA.z = redsum2(accA.z * rq); accA.w = redsum2(accA.w * rq);
    accB.x = redsum2(accB.x * rq); accB.y = redsum2(accB.y * rq);
    accB.z = redsum2(accB.z * rq); accB.w = redsum2(accB.w * rq);
    const float inv = XINV / (sq + 1e-16f);   // undo message scaling

    if (!LAST) {
        if (q == 0) {
            const float4 bA = *(const float4*)(b + cb);
            const float4 bB = *(const float4*)(b + cb + 4);
            float4 oA, oB;
            oA.x = accA.x * inv + bA.x; oA.x = oA.x > 0.f ? oA.x : expm1f(oA.x);
            oA.y = accA.y * inv + bA.y; oA.y = oA.y > 0.f ? oA.y : expm1f(oA.y);
            oA.z = accA.z * inv + bA.z; oA.z = oA.z > 0.f ? oA.z : expm1f(oA.z);
            oA.w = accA.w * inv + bA.w; oA.w = oA.w > 0.f ? oA.w : expm1f(oA.w);
            oB.x = accB.x * inv + bB.x; oB.x = oB.x > 0.f ? oB.x : expm1f(oB.x);
            oB.y = accB.y * inv + bB.y; oB.y = oB.y > 0.f ? oB.y : expm1f(oB.y);
            oB.z = accB.z * inv + bB.z; oB.z = oB.z > 0.f ? oB.z : expm1f(oB.z);
            oB.w = accB.w * inv + bB.w; oB.w = oB.w > 0.f ? oB.w : expm1f(oB.w);
            float* op = xout + (size_t)node * 128;
            *(float4*)(op + cb)     = oA;
            *(float4*)(op + cb + 4) = oB;
        }
    } else {
        // mean over heads: bring other head's normalized value via stride-8 shfl
        float oA[4] = {accA.x * inv, accA.y * inv, accA.z * inv, accA.w * inv};
        float oB[4] = {accB.x * inv, accB.y * inv, accB.z * inv, accB.w * inv};
        float pA[4], pB[4];
#pragma unroll
        for (int k = 0; k < 4; ++k) {
            pA[k] = __shfl_xor(oA[k], 8, 64);
            pB[k] = __shfl_xor(oB[k], 8, 64);
        }
        if (q == 0 && h == 0) {
            const float4 bA = *(const float4*)(b + j * 8);
            const float4 bB = *(const float4*)(b + j * 8 + 4);
            float* op = xout + (size_t)widx * 64 + j * 8;
            op[0] = 0.5f * (oA[0] + pA[0]) + bA.x;
            op[1] = 0.5f * (oA[1] + pA[1]) + bA.y;
            op[2] = 0.5f * (oA[2] + pA[2]) + bA.z;
            op[3] = 0.5f * (oA[3] + pA[3]) + bA.w;
            op[4] = 0.5f * (oB[0] + pB[0]) + bB.x;
            op[5] = 0.5f * (oB[1] + pB[1]) + bB.y;
            op[6] = 0.5f * (oB[2] + pB[2]) + bB.z;
            op[7] = 0.5f * (oB[3] + pB[3]) + bB.w;
        }
    }
}

extern "C" void kernel_launch(void* const* d_in, const int* in_sizes, int n_in,
                              void* d_out, int out_size, void* d_ws, size_t ws_size,
                              hipStream_t stream)
{
    const int*   pert = (const int*)d_in[0];
    const int*   eidx = (const int*)d_in[1];
    const float* ew   = (const float*)d_in[2];
    const float* emb  = (const float*)d_in[3];
    const float* Wl[4] = {(const float*)d_in[4],  (const float*)d_in[8],
                          (const float*)d_in[12], (const float*)d_in[16]};
    const float* Wr[4] = {(const float*)d_in[5],  (const float*)d_in[9],
                          (const float*)d_in[13], (const float*)d_in[17]};
    const float* av[4] = {(const float*)d_in[6],  (const float*)d_in[10],
                          (const float*)d_in[14], (const float*)d_in[18]};
    const float* bv[4] = {(const float*)d_in[7],  (const float*)d_in[11],
                          (const float*)d_in[15], (const float*)d_in[19]};

    const int N = N_NODES, E = N_EDGES;
    const int* srcp = eidx;
    const int* dstp = eidx + E;

    // workspace layout
    float*  ws   = (float*)d_ws;
    float*  xbuf = ws;                                // N*128 f
    __half* xlh  = (__half*)(xbuf + (size_t)N * 128); // N*128 h (fp16 * XSCALE)
    float*  xr   = (float*)(xlh + (size_t)N * 128);   // N*128 f
    short*  wpk  = (short*)(xr + (size_t)N * 128);    // 4 layers x 65536 shorts
    int*    deg  = (int*)(wpk + 4 * 65536);           // N
    int*    off  = deg + N;                           // N+1
    int*    cur  = off + N + 1;                       // N
    int*    ssrc = cur + N;                           // E
    float*  sew  = (float*)(ssrc + E);                // E

    // ---- prep (zero deg + pack all W) then CSR build
    prep_kernel<<<(N + 14336 + 255) / 256, 256, 0, stream>>>(
        deg, Wl[0], Wr[0], Wl[1], Wr[1], Wl[2], Wr[2], Wl[3], Wr[3], wpk);
    count_deg_kernel<<<(E + 255) / 256, 256, 0, stream>>>(dstp, deg, E);
    scan_kernel<<<1, 1024, 0, stream>>>(deg, off, cur);
    scatter_kernel<<<(E + 255) / 256, 256, 0, stream>>>(srcp, dstp, ew, cur,
                                                        ssrc, sew, E);

    // ---- layer 0 (K=64)
    mfma_transform_kernel<2, 4><<<MTILES, 256, 0, stream>>>(emb, wpk, xlh, xr);
    gat_node_kernel<0><<<(N * 64 + 255) / 256, 256, 0, stream>>>(
        xlh, xr, off, ssrc, sew, av[0], bv[0], xbuf, nullptr, N);

    // ---- layers 1,2 (K=128)
    for (int layer = 1; layer < 3; ++layer) {
        mfma_transform_kernel<4, 4><<<MTILES, 256, 0, stream>>>(
            xbuf, wpk + layer * 65536, xlh, xr);
        gat_node_kernel<0><<<(N * 64 + 255) / 256, 256, 0, stream>>>(
            xlh, xr, off, ssrc, sew, av[layer], bv[layer], xbuf, nullptr, N);
    }

    // ---- layer 3: fused {xl MFMA transform | xr pert rows}, then gat
    l3_fused_kernel<<<MTILES + BATCH / 8, 128, 0, stream>>>(
        xbuf, wpk + 3 * 65536, xlh, pert, Wr[3], xr);
    gat_node_kernel<1><<<(BATCH * 64 + 255) / 256, 256, 0, stream>>>(
        xlh, xr, off, ssrc, sew, av[3], bv[3], (float*)d_out, pert, BATCH);
}

// Round 18
// 220.942 us; speedup vs baseline: 1.3147x; 1.0620x over previous
//
#include <hip/hip_runtime.h>
#include <hip/hip_fp16.h>
#include <math.h>

#define N_NODES 20000
#define N_EDGES 400000
#define BATCH   4096
#define MTILES  (N_NODES / 16)   // 1250
#define XSCALE  1024.0f
#define XINV    (1.0f / 1024.0f)

typedef __attribute__((ext_vector_type(8))) short short8v;
typedef __attribute__((ext_vector_type(4))) float f32x4;
typedef __attribute__((ext_vector_type(2))) _Float16 h2v;

// fp16 dot-pair with fp32 accumulate (v_dot2_f32_f16); fp32 fallback if absent
__device__ __forceinline__ float fdot2h(h2v a, h2v b, float c)
{
#if __has_builtin(__builtin_amdgcn_fdot2)
    return __builtin_amdgcn_fdot2(a, b, c, false);
#else
    return fmaf((float)a[0], (float)b[0], fmaf((float)a[1], (float)b[1], c));
#endif
}

__device__ __forceinline__ h2v mk_h2(float x, float y)
{
    h2v r; r[0] = (_Float16)x; r[1] = (_Float16)y; return r;
}

// ---- split fp32 into bf16 hi + bf16 lo (truncation; hi+lo ~ 16 mantissa bits)
__device__ __forceinline__ void bf16split(float v, short& h, short& l)
{
    unsigned u  = __float_as_uint(v);
    unsigned hu = u & 0xFFFF0000u;
    h = (short)(hu >> 16);
    const float lo = v - __uint_as_float(hu);
    l = (short)(__float_as_uint(lo) >> 16);
}

// ---- prep: zero deg (t < N_NODES) + pack ALL 4 layers' W into B-fragments
__global__ __launch_bounds__(256)
void prep_kernel(int* __restrict__ deg,
                 const float* __restrict__ Wl0, const float* __restrict__ Wr0,
                 const float* __restrict__ Wl1, const float* __restrict__ Wr1,
                 const float* __restrict__ Wl2, const float* __restrict__ Wr2,
                 const float* __restrict__ Wl3, const float* __restrict__ Wr3,
                 short* __restrict__ wpk)
{
    const int t = blockIdx.x * 256 + threadIdx.x;
    if (t < N_NODES) { deg[t] = 0; return; }
    const int tp = t - N_NODES;
    if (tp >= 14336) return;
    int layer, base, K;
    const float *Wl, *Wr;
    if (tp < 2048)       { layer = 0; base = 0;     K = 64;  Wl = Wl0; Wr = Wr0; }
    else if (tp < 6144)  { layer = 1; base = 2048;  K = 128; Wl = Wl1; Wr = Wr1; }
    else if (tp < 10240) { layer = 2; base = 6144;  K = 128; Wl = Wl2; Wr = Wr2; }
    else                 { layer = 3; base = 10240; K = 128; Wl = Wl3; Wr = Wr3; }
    const int KB   = K / 32;
    const int tt   = tp - base;
    const int lane = tt & 63;
    const int kb   = (tt >> 6) % KB;
    const int nt   = tt / (64 * KB);
    const float* W = (nt < 8) ? Wl : Wr;
    const int col  = (nt & 7) * 16 + (lane & 15);
    const int k0   = kb * 32 + (lane >> 4) * 8;
    short8v h, l;
#pragma unroll
    for (int e = 0; e < 8; ++e) {
        short hh, ll; bf16split(W[(size_t)(k0 + e) * 128 + col], hh, ll);
        h[e] = hh; l[e] = ll;
    }
    short* ob = wpk + (size_t)layer * 65536
                    + ((size_t)(nt * KB + kb) * 2) * 512 + lane * 8;
    *(short8v*)ob         = h;
    *(short8v*)(ob + 512) = l;
}

// ---- MFMA transform with fused x packing (LDS stage, bf16 hi/lo in-reg,
// bf16x3 compensation). xl written as fp16 * XSCALE; xr stays fp32.
template<int KB, int NWAVES>
__global__ __launch_bounds__(NWAVES * 64)
void mfma_transform_kernel(const float* __restrict__ x,
                           const short* __restrict__ wpk,
                           __half* __restrict__ xlh, float* __restrict__ xr)
{
    constexpr int K  = KB * 32;
    constexpr int KP = K + 4;
    __shared__ float xs[16 * KP];
    const int mtile = blockIdx.x;
    const int wid   = threadIdx.x >> 6;
    const int lane  = threadIdx.x & 63;

    {
        const float4* __restrict__ src = (const float4*)(x + (size_t)mtile * 16 * K);
        for (int idx = threadIdx.x; idx < 16 * K / 4; idx += NWAVES * 64) {
            const int row = idx / (K / 4), c4 = idx % (K / 4);
            *(float4*)(xs + row * KP + c4 * 4) = src[idx];
        }
    }
    __syncthreads();

    short8v ah[KB], al[KB];
    {
        const float* ab = xs + (lane & 15) * KP + (lane >> 4) * 8;
#pragma unroll
        for (int kb = 0; kb < KB; ++kb) {
            const float4 f0 = *(const float4*)(ab + kb * 32);
            const float4 f1 = *(const float4*)(ab + kb * 32 + 4);
            float tmp[8] = {f0.x, f0.y, f0.z, f0.w, f1.x, f1.y, f1.z, f1.w};
#pragma unroll
            for (int e = 0; e < 8; ++e) {
                short hh, ll; bf16split(tmp[e], hh, ll);
                ah[kb][e] = hh; al[kb][e] = ll;
            }
        }
    }

#pragma unroll
    for (int i = 0; i < 4; ++i) {
        const int nt = wid * 4 + i;
        const short* bb = wpk + ((size_t)nt * KB * 2) * 512 + lane * 8;
        f32x4 acc = {0.f, 0.f, 0.f, 0.f};
#pragma unroll
        for (int kb = 0; kb < KB; ++kb) {
            const short8v bh = *(const short8v*)(bb + (size_t)(kb * 2 + 0) * 512);
            const short8v bl = *(const short8v*)(bb + (size_t)(kb * 2 + 1) * 512);
            acc = __builtin_amdgcn_mfma_f32_16x16x32_bf16(ah[kb], bh, acc, 0, 0, 0);
            acc = __builtin_amdgcn_mfma_f32_16x16x32_bf16(ah[kb], bl, acc, 0, 0, 0);
            acc = __builtin_amdgcn_mfma_f32_16x16x32_bf16(al[kb], bh, acc, 0, 0, 0);
        }
        const int colb = (nt & 7) * 16 + (lane & 15);
        const int row0 = mtile * 16 + (lane >> 4) * 4;
        if (nt < 8) {
#pragma unroll
            for (int r = 0; r < 4; ++r)
                xlh[(size_t)(row0 + r) * 128 + colb] = __float2half(acc[r] * XSCALE);
        } else {
#pragma unroll
            for (int r = 0; r < 4; ++r)
                xr[(size_t)(row0 + r) * 128 + colb] = acc[r];
        }
    }
}

// ---- layer 3 fused: blocks [0,MTILES) = MFMA xl transform (2 waves, xl only);
// blocks [MTILES, MTILES+BATCH/8) = xr for pert rows (scalar pipelined).
__global__ __launch_bounds__(128)
void l3_fused_kernel(const float* __restrict__ x, const short* __restrict__ wpk,
                     __half* __restrict__ xlh,
                     const int* __restrict__ pert, const float* __restrict__ Wr3,
                     float* __restrict__ xr)
{
    constexpr int K  = 128;
    constexpr int KP = K + 4;
    __shared__ float xs[16 * KP];

    if (blockIdx.x < MTILES) {
        const int mtile = blockIdx.x;
        const int wid   = threadIdx.x >> 6;
        const int lane  = threadIdx.x & 63;
        {
            const float4* __restrict__ src = (const float4*)(x + (size_t)mtile * 16 * K);
            for (int idx = threadIdx.x; idx < 16 * K / 4; idx += 128) {
                const int row = idx / (K / 4), c4 = idx % (K / 4);
                *(float4*)(xs + row * KP + c4 * 4) = src[idx];
            }
        }
        __syncthreads();

        short8v ah[4], al[4];
        {
            const float* ab = xs + (lane & 15) * KP + (lane >> 4) * 8;
#pragma unroll
            for (int kb = 0; kb < 4; ++kb) {
                const float4 f0 = *(const float4*)(ab + kb * 32);
                const float4 f1 = *(const float4*)(ab + kb * 32 + 4);
                float tmp[8] = {f0.x, f0.y, f0.z, f0.w, f1.x, f1.y, f1.z, f1.w};
#pragma unroll
                for (int e = 0; e < 8; ++e) {
                    short hh, ll; bf16split(tmp[e], hh, ll);
                    ah[kb][e] = hh; al[kb][e] = ll;
                }
            }
        }
#pragma unroll
        for (int i = 0; i < 4; ++i) {
            const int nt = wid * 4 + i;       // 0..7: xl tiles only
            const short* bb = wpk + ((size_t)nt * 4 * 2) * 512 + lane * 8;
            f32x4 acc = {0.f, 0.f, 0.f, 0.f};
#pragma unroll
            for (int kb = 0; kb < 4; ++kb) {
                const short8v bh = *(const short8v*)(bb + (size_t)(kb * 2 + 0) * 512);
                const short8v bl = *(const short8v*)(bb + (size_t)(kb * 2 + 1) * 512);
                acc = __builtin_amdgcn_mfma_f32_16x16x32_bf16(ah[kb], bh, acc, 0, 0, 0);
                acc = __builtin_amdgcn_mfma_f32_16x16x32_bf16(ah[kb], bl, acc, 0, 0, 0);
                acc = __builtin_amdgcn_mfma_f32_16x16x32_bf16(al[kb], bh, acc, 0, 0, 0);
            }
            const int colb = (nt & 7) * 16 + (lane & 15);
            const int row0 = mtile * 16 + (lane >> 4) * 4;
#pragma unroll
            for (int r = 0; r < 4; ++r)
                xlh[(size_t)(row0 + r) * 128 + colb] = __float2half(acc[r] * XSCALE);
        }
    } else {
        constexpr int G = 8;
        const int t  = threadIdx.x;
        const int i0 = (blockIdx.x - MTILES) * G;

        const float* __restrict__ xrow[G];
#pragma unroll
        for (int g = 0; g < G; ++g)
            xrow[g] = x + (size_t)pert[i0 + g] * K;

        float acc[G];
#pragma unroll
        for (int g = 0; g < G; ++g) acc[g] = 0.f;

        float4 xA[G], xB[G];
        float wA[4], wB[4];

        auto loadc = [&](float4* xv, float* w, int k) {
#pragma unroll
            for (int g = 0; g < G; ++g)
                xv[g] = *(const float4*)(xrow[g] + k);
#pragma unroll
            for (int u = 0; u < 4; ++u) w[u] = Wr3[(k + u) * 128 + t];
        };
        auto fmac = [&](const float4* xv, const float* w) {
#pragma unroll
            for (int g = 0; g < G; ++g) {
                acc[g] = fmaf(xv[g].x, w[0], acc[g]);
                acc[g] = fmaf(xv[g].y, w[1], acc[g]);
                acc[g] = fmaf(xv[g].z, w[2], acc[g]);
                acc[g] = fmaf(xv[g].w, w[3], acc[g]);
            }
        };

        loadc(xA, wA, 0);
        for (int k0 = 0; k0 < K; k0 += 8) {
            if (k0 + 4 < K) loadc(xB, wB, k0 + 4);
            fmac(xA, wA);
            if (k0 + 8 < K) loadc(xA, wA, k0 + 8);
            fmac(xB, wB);
        }
#pragma unroll
        for (int g = 0; g < G; ++g)
            xr[(size_t)(i0 + g) * 128 + t] = acc[g];
    }
}

// ---- CSR build: count degrees
__global__ __launch_bounds__(256)
void count_deg_kernel(const int* __restrict__ dst, int* __restrict__ deg, int E)
{
    const int e = blockIdx.x * blockDim.x + threadIdx.x;
    if (e < E) atomicAdd(&deg[dst[e]], 1);
}

// ---- exclusive scan over 20000 degrees; one block, LDS-staged coalesced I/O.
#define CHUNK 20
#define SCAN_PAD (1024 * CHUNK)
__global__ __launch_bounds__(1024)
void scan_kernel(const int* __restrict__ deg, int* __restrict__ off,
                 int* __restrict__ cursor)
{
    __shared__ int xs[SCAN_PAD];
    __shared__ int sums[1024];
    const int t = threadIdx.x;
    for (int i = t; i < SCAN_PAD; i += 1024)
        xs[i] = (i < N_NODES) ? deg[i] : 0;
    __syncthreads();

    const int base = t * CHUNK;
    int local[CHUNK];
    int s = 0;
#pragma unroll
    for (int i = 0; i < CHUNK; ++i) {
        local[i] = s;
        s += xs[base + i];
    }
    sums[t] = s;
    __syncthreads();
    for (int d = 1; d < 1024; d <<= 1) {
        int v = (t >= d) ? sums[t - d] : 0;
        __syncthreads();
        sums[t] += v;
        __syncthreads();
    }
    const int prev = (t == 0) ? 0 : sums[t - 1];
#pragma unroll
    for (int i = 0; i < CHUNK; ++i)
        xs[base + i] = prev + local[i];
    __syncthreads();
    for (int i = t; i < N_NODES; i += 1024) {
        const int o = xs[i];
        off[i] = o;
        cursor[i] = o;
    }
    if (t == 1023) off[N_NODES] = sums[1023];
}

// ---- scatter edges into dst-sorted order
__global__ __launch_bounds__(256)
void scatter_kernel(const int* __restrict__ src, const int* __restrict__ dst,
                    const float* __restrict__ ew, int* __restrict__ cursor,
                    int* __restrict__ ssrc, float* __restrict__ sew, int E)
{
    const int e = blockIdx.x * blockDim.x + threadIdx.x;
    if (e >= E) return;
    const int p = atomicAdd(&cursor[dst[e]], 1);
    ssrc[p] = src[e];
    sew[p]  = ew[e];
}

// ---- fused GATv2 layer: one wave per dst node, 4 edge slots (lane =
// q*16 + h*8 + j). Packed-fp16 score path via ext-vector _Float16 arithmetic
// (v_pk_add/mul + __builtin_elementwise_max -> v_pk_max) and v_dot2_f32_f16.
// Defer-max online softmax (T13). Messages accumulate fp32 in scaled space.
template<int LAST>
__global__ __launch_bounds__(256)
void gat_node_kernel(const __half* __restrict__ xl, const float* __restrict__ xr,
                     const int* __restrict__ off, const int* __restrict__ ssrc,
                     const float* __restrict__ sew, const float* __restrict__ a,
                     const float* __restrict__ b, float* __restrict__ xout,
                     const int* __restrict__ nodemap, int nnodes)
{
    const int widx = (int)((blockIdx.x * blockDim.x + threadIdx.x) >> 6);
    if (widx >= nnodes) return;
    const int node = LAST ? nodemap[widx] : widx;
    const int xrrow = widx;          // == node for !LAST; batch row for LAST
    const int lane = threadIdx.x & 63;
    const int q  = lane >> 4;        // edge slot (4)
    const int h  = (lane >> 3) & 1;  // head
    const int j  = lane & 7;
    const int cb = h * 64 + j * 8;   // this lane's 8 dims

    // r (scaled) and a as fp16 pairs, converted once per wave
    const float* xrp = xr + (size_t)xrrow * 128 + cb;
    const h2v r01 = mk_h2(xrp[0] * XSCALE, xrp[1] * XSCALE);
    const h2v r23 = mk_h2(xrp[2] * XSCALE, xrp[3] * XSCALE);
    const h2v r45 = mk_h2(xrp[4] * XSCALE, xrp[5] * XSCALE);
    const h2v r67 = mk_h2(xrp[6] * XSCALE, xrp[7] * XSCALE);
    const h2v a01 = mk_h2(a[cb],     a[cb + 1]);
    const h2v a23 = mk_h2(a[cb + 2], a[cb + 3]);
    const h2v a45 = mk_h2(a[cb + 4], a[cb + 5]);
    const h2v a67 = mk_h2(a[cb + 6], a[cb + 7]);

    const int e0 = off[node], e1 = off[node + 1];
    const int nr = (e1 - e0 + 3) >> 2;   // rounds

    float m = -1e30f, s = 0.f;
    float4 accA = {0,0,0,0}, accB = {0,0,0,0};

    auto lde = [&](int r, float& w, bool& valid, uint4& raw) {
        const int ei  = e0 + r * 4 + q;
        valid = ei < e1;
        const int eic = valid ? ei : (e1 - 1);
        const int sn  = ssrc[eic];
        w = valid ? sew[eic] : 0.f;
        raw = *(const uint4*)(xl + (size_t)sn * 128 + cb);
    };
    auto plrelu = [](h2v v) {
        return __builtin_elementwise_max(v, v * (_Float16)0.2f);
    };

    float w_c; bool v_c; uint4 raw_c;
    if (nr > 0) lde(0, w_c, v_c, raw_c);

    for (int r = 0; r < nr; ++r) {
        float w_n; bool v_n; uint4 raw_n;
        if (r + 1 < nr) lde(r + 1, w_n, v_n, raw_n);   // issue-early

        const h2v x01 = __builtin_bit_cast(h2v, raw_c.x);
        const h2v x23 = __builtin_bit_cast(h2v, raw_c.y);
        const h2v x45 = __builtin_bit_cast(h2v, raw_c.z);
        const h2v x67 = __builtin_bit_cast(h2v, raw_c.w);

        // packed score path: v = lrelu(x + r), p = sum v*a (fp32 acc)
        const h2v v01 = plrelu(x01 + r01);
        const h2v v23 = plrelu(x23 + r23);
        const h2v v45 = plrelu(x45 + r45);
        const h2v v67 = plrelu(x67 + r67);
        float p = fdot2h(v01, a01, 0.f);
        p = fdot2h(v23, a23, p);
        p = fdot2h(v45, a45, p);
        p = fdot2h(v67, a67, p);
        p += __shfl_xor(p, 1, 64);
        p += __shfl_xor(p, 2, 64);
        p += __shfl_xor(p, 4, 64);       // per-8-lane group: own head's score
        p = v_c ? p * XINV : -1e30f;     // exact unscale (lrelu pos-homogeneous)

        // fp32 x for message accumulation
        const float f0x = (float)x01[0], f0y = (float)x01[1];
        const float f1x = (float)x23[0], f1y = (float)x23[1];
        const float f2x = (float)x45[0], f2y = (float)x45[1];
        const float f3x = (float)x67[0], f3y = (float)x67[1];

        const float d = p - m;           // group-uniform
        if (__any(d > 8.f)) {
            // slow path (rare): full online update with rescale
            const float t   = __expf(-fabsf(d));
            const bool  pos = d > 0.f;
            const float rr  = pos ? t : 1.f;
            const float ex  = pos ? 1.f : t;
            m = pos ? p : m;
            const float c = ex * w_c;
            s = s * rr + ex;
            accA.x = fmaf(c, f0x, accA.x * rr); accA.y = fmaf(c, f0y, accA.y * rr);
            accA.z = fmaf(c, f1x, accA.z * rr); accA.w = fmaf(c, f1y, accA.w * rr);
            accB.x = fmaf(c, f2x, accB.x * rr); accB.y = fmaf(c, f2y, accB.y * rr);
            accB.z = fmaf(c, f3x, accB.z * rr); accB.w = fmaf(c, f3y, accB.w * rr);
        } else {
            // fast path: d <= 8 for every group -> no rescale needed
            const float ex = __expf(d);
            const float c  = ex * w_c;
            s += ex;
            accA.x = fmaf(c, f0x, accA.x); accA.y = fmaf(c, f0y, accA.y);
            accA.z = fmaf(c, f1x, accA.z); accA.w = fmaf(c, f1y, accA.w);
            accB.x = fmaf(c, f2x, accB.x); accB.y = fmaf(c, f2y, accB.y);
            accB.z = fmaf(c, f3x, accB.z); accB.w = fmaf(c, f3y, accB.w);
        }

        w_c = w_n; v_c = v_n; raw_c = raw_n;
    }

    // ---- merge the 4 slot states (across q: lane strides 16, 32)
    float mg = fmaxf(m, __shfl_xor(m, 16, 64));
    mg = fmaxf(mg, __shfl_xor(mg, 32, 64));
    const float rq = __expf(m - mg);     // 0 for dead slots
    float sq = s * rq;
    sq += __shfl_xor(sq, 16, 64);
    sq += __shfl_xor(sq, 32, 64);
    auto redsum2 = [](float v) {
        v += __shfl_xor(v, 16, 64);
        return v + __shfl_xor(v, 32, 64);
    };
    accA.x = redsum2(accA.x * rq); accA.y = redsum2(accA.y * rq);
    accA.z = redsum2(accA.z * rq); accA.w = redsum2(accA.w * rq);
    accB.x = redsum2(accB.x * rq); accB.y = redsum2(accB.y * rq);
    accB.z = redsum2(accB.z * rq); accB.w = redsum2(accB.w * rq);
    const float inv = XINV / (sq + 1e-16f);   // undo message scaling

    if (!LAST) {
        if (q == 0) {
            const float4 bA = *(const float4*)(b + cb);
            const float4 bB = *(const float4*)(b + cb + 4);
            float4 oA, oB;
            oA.x = accA.x * inv + bA.x; oA.x = oA.x > 0.f ? oA.x : expm1f(oA.x);
            oA.y = accA.y * inv + bA.y; oA.y = oA.y > 0.f ? oA.y : expm1f(oA.y);
            oA.z = accA.z * inv + bA.z; oA.z = oA.z > 0.f ? oA.z : expm1f(oA.z);
            oA.w = accA.w * inv + bA.w; oA.w = oA.w > 0.f ? oA.w : expm1f(oA.w);
            oB.x = accB.x * inv + bB.x; oB.x = oB.x > 0.f ? oB.x : expm1f(oB.x);
            oB.y = accB.y * inv + bB.y; oB.y = oB.y > 0.f ? oB.y : expm1f(oB.y);
            oB.z = accB.z * inv + bB.z; oB.z = oB.z > 0.f ? oB.z : expm1f(oB.z);
            oB.w = accB.w * inv + bB.w; oB.w = oB.w > 0.f ? oB.w : expm1f(oB.w);
            float* op = xout + (size_t)node * 128;
            *(float4*)(op + cb)     = oA;
            *(float4*)(op + cb + 4) = oB;
        }
    } else {
        // mean over heads: bring other head's normalized value via stride-8 shfl
        float oA[4] = {accA.x * inv, accA.y * inv, accA.z * inv, accA.w * inv};
        float oB[4] = {accB.x * inv, accB.y * inv, accB.z * inv, accB.w * inv};
        float pA[4], pB[4];
#pragma unroll
        for (int k = 0; k < 4; ++k) {
            pA[k] = __shfl_xor(oA[k], 8, 64);
            pB[k] = __shfl_xor(oB[k], 8, 64);
        }
        if (q == 0 && h == 0) {
            const float4 bA = *(const float4*)(b + j * 8);
            const float4 bB = *(const float4*)(b + j * 8 + 4);
            float* op = xout + (size_t)widx * 64 + j * 8;
            op[0] = 0.5f * (oA[0] + pA[0]) + bA.x;
            op[1] = 0.5f * (oA[1] + pA[1]) + bA.y;
            op[2] = 0.5f * (oA[2] + pA[2]) + bA.z;
            op[3] = 0.5f * (oA[3] + pA[3]) + bA.w;
            op[4] = 0.5f * (oB[0] + pB[0]) + bB.x;
            op[5] = 0.5f * (oB[1] + pB[1]) + bB.y;
            op[6] = 0.5f * (oB[2] + pB[2]) + bB.z;
            op[7] = 0.5f * (oB[3] + pB[3]) + bB.w;
        }
    }
}

extern "C" void kernel_launch(void* const* d_in, const int* in_sizes, int n_in,
                              void* d_out, int out_size, void* d_ws, size_t ws_size,
                              hipStream_t stream)
{
    const int*   pert = (const int*)d_in[0];
    const int*   eidx = (const int*)d_in[1];
    const float* ew   = (const float*)d_in[2];
    const float* emb  = (const float*)d_in[3];
    const float* Wl[4] = {(const float*)d_in[4],  (const float*)d_in[8],
                          (const float*)d_in[12], (const float*)d_in[16]};
    const float* Wr[4] = {(const float*)d_in[5],  (const float*)d_in[9],
                          (const float*)d_in[13], (const float*)d_in[17]};
    const float* av[4] = {(const float*)d_in[6],  (const float*)d_in[10],
                          (const float*)d_in[14], (const float*)d_in[18]};
    const float* bv[4] = {(const float*)d_in[7],  (const float*)d_in[11],
                          (const float*)d_in[15], (const float*)d_in[19]};

    const int N = N_NODES, E = N_EDGES;
    const int* srcp = eidx;
    const int* dstp = eidx + E;

    // workspace layout
    float*  ws   = (float*)d_ws;
    float*  xbuf = ws;                                // N*128 f
    __half* xlh  = (__half*)(xbuf + (size_t)N * 128); // N*128 h (fp16 * XSCALE)
    float*  xr   = (float*)(xlh + (size_t)N * 128);   // N*128 f
    short*  wpk  = (short*)(xr + (size_t)N * 128);    // 4 layers x 65536 shorts
    int*    deg  = (int*)(wpk + 4 * 65536);           // N
    int*    off  = deg + N;                           // N+1
    int*    cur  = off + N + 1;                       // N
    int*    ssrc = cur + N;                           // E
    float*  sew  = (float*)(ssrc + E);                // E

    // ---- prep (zero deg + pack all W) then CSR build
    prep_kernel<<<(N + 14336 + 255) / 256, 256, 0, stream>>>(
        deg, Wl[0], Wr[0], Wl[1], Wr[1], Wl[2], Wr[2], Wl[3], Wr[3], wpk);
    count_deg_kernel<<<(E + 255) / 256, 256, 0, stream>>>(dstp, deg, E);
    scan_kernel<<<1, 1024, 0, stream>>>(deg, off, cur);
    scatter_kernel<<<(E + 255) / 256, 256, 0, stream>>>(srcp, dstp, ew, cur,
                                                        ssrc, sew, E);

    // ---- layer 0 (K=64)
    mfma_transform_kernel<2, 4><<<MTILES, 256, 0, stream>>>(emb, wpk, xlh, xr);
    gat_node_kernel<0><<<(N * 64 + 255) / 256, 256, 0, stream>>>(
        xlh, xr, off, ssrc, sew, av[0], bv[0], xbuf, nullptr, N);

    // ---- layers 1,2 (K=128)
    for (int layer = 1; layer < 3; ++layer) {
        mfma_transform_kernel<4, 4><<<MTILES, 256, 0, stream>>>(
            xbuf, wpk + layer * 65536, xlh, xr);
        gat_node_kernel<0><<<(N * 64 + 255) / 256, 256, 0, stream>>>(
            xlh, xr, off, ssrc, sew, av[layer], bv[layer], xbuf, nullptr, N);
    }

    // ---- layer 3: fused {xl MFMA transform | xr pert rows}, then gat
    l3_fused_kernel<<<MTILES + BATCH / 8, 128, 0, stream>>>(
        xbuf, wpk + 3 * 65536, xlh, pert, Wr[3], xr);
    gat_node_kernel<1><<<(BATCH * 64 + 255) / 256, 256, 0, stream>>>(
        xlh, xr, off, ssrc, sew, av[3], bv[3], (float*)d_out, pert, BATCH);
}